// Round 1
// baseline (2018.248 us; speedup 1.0000x reference)
//
#include <hip/hip_runtime.h>
#include <math.h>

// ---------------------------------------------------------------------------
// TGAT classifier, f32 correctness-first implementation.
// Key algebraic reductions (exact reassociations of the reference):
//  - query length is 1 => fold wq,wk (and W_lin,b_lin for the raw-feature
//    call) into per-head score matrices: score = gf.f + gte.te + sb where
//    [gf|gte|sb] = src @ SW.T + cb   (SW: [520,128], 2 heads x 260)
//  - softmax weights sum to 1 => aggregate in input space (yraw,yte per head),
//    then wv, W_lin, fc_w fold into one matrix F [256,520]:
//    out2 = Y @ F.T  (Y = [yraw0,yte0,1,0,0,0, yraw1,yte1,1,0,0,0])
// ---------------------------------------------------------------------------

__global__ __launch_bounds__(128) void k_te0(const float* phase, float* te0) {
  int t = threadIdx.x;
  if (t < 128) te0[t] = cosf(phase[t]);
}

// naive small gemm: C[i][j] = sum_k Aop[i][k] * B[k*ldb+j]
// Aop = transA ? A[k*lda+i] : A[i*lda+k]
__global__ __launch_bounds__(256) void k_sgemm_naive(
    const float* __restrict__ A, const float* __restrict__ B, float* __restrict__ C,
    int M, int N, int K, int lda, int ldb, int ldc, int transA)
{
  int idx = blockIdx.x * 256 + threadIdx.x;
  if (idx >= M * N) return;
  int i = idx / N, j = idx % N;
  float s = 0.f;
  if (transA) {
    for (int k = 0; k < K; k++) s += A[(size_t)k * lda + i] * B[(size_t)k * ldb + j];
  } else {
    for (int k = 0; k < K; k++) s += A[(size_t)i * lda + k] * B[(size_t)k * ldb + j];
  }
  C[(size_t)i * ldc + j] = s;
}

// SW [520][128], cb[520] from M2 [2][256][128], c2 [2][256]
__global__ __launch_bounds__(256) void k_build_SW(
    float* __restrict__ SW, float* __restrict__ cb,
    const float* __restrict__ M2, const float* __restrict__ c2,
    const float* __restrict__ Wlin, const float* __restrict__ blin, int uselin)
{
  int idx = blockIdx.x * 256 + threadIdx.x;
  if (idx >= 520 * 128) return;
  int urow = idx / 128, s = idx % 128;
  int h = urow / 260, u = urow % 260;
  const float* M = M2 + (size_t)h * 256 * 128;
  const float* c = c2 + h * 256;
  float val = 0.f, cbv = 0.f;
  if (u < 128) {
    if (uselin) {
      for (int cc = 0; cc < 128; cc++) {
        float w = Wlin[cc * 128 + u];
        val += w * M[cc * 128 + s];
        cbv += w * c[cc];
      }
    } else { val = M[u * 128 + s]; cbv = c[u]; }
  } else if (u < 256) {
    val = M[u * 128 + s]; cbv = c[u];
  } else if (u == 256) {
    if (uselin) {
      for (int cc = 0; cc < 128; cc++) {
        float w = blin[cc];
        val += w * M[cc * 128 + s];
        cbv += w * c[cc];
      }
    }
  }
  SW[(size_t)urow * 128 + s] = val;
  if (s == 0) cb[urow] = cbv;
}

// OW [2][128][260] from wv (layer base [256][256])
__global__ __launch_bounds__(256) void k_build_OW(
    float* __restrict__ OW, const float* __restrict__ wv,
    const float* __restrict__ Wlin, const float* __restrict__ blin, int uselin)
{
  int idx = blockIdx.x * 256 + threadIdx.x;
  if (idx >= 2 * 128 * 260) return;
  int u = idx % 260; int d = (idx / 260) % 128; int h = idx / (260 * 128);
  const float* wr = wv + (size_t)(h * 128 + d) * 256;
  float val = 0.f;
  if (u < 128) {
    if (uselin) { for (int cc = 0; cc < 128; cc++) val += wr[cc] * Wlin[cc * 128 + u]; }
    else val = wr[u];
  } else if (u < 256) {
    val = wr[u];
  } else if (u == 256) {
    if (uselin) { for (int cc = 0; cc < 128; cc++) val += wr[cc] * blin[cc]; }
  }
  OW[idx] = val;
}

// tiled f32 GEMM: C[M,N] = Acat[M,K] @ B[N,K].T (+bias) (+relu)
// Acat col k: k<splitK -> A[r*lda+k], else A2[r*lda2+k-splitK]
__global__ __launch_bounds__(256) void k_gemm64(
    const float* __restrict__ A, const float* __restrict__ A2, int splitK,
    int lda, int lda2,
    const float* __restrict__ B, int ldb,
    const float* __restrict__ bias,
    float* __restrict__ C, int ldc,
    int M, int N, int K, int relu)
{
  __shared__ __align__(16) float As[16][68];
  __shared__ __align__(16) float Bs[16][68];
  int tid = threadIdx.x;
  int tm = tid >> 4, tn = tid & 15;
  int row0 = blockIdx.x * 64, col0 = blockIdx.y * 64;
  int lrow = tid >> 2;
  int lk = (tid & 3) << 2;
  float acc[4][4] = {{0.f}};
  for (int k0 = 0; k0 < K; k0 += 16) {
    int ka = k0 + lk;
    float4 av = make_float4(0.f, 0.f, 0.f, 0.f);
    int ar = row0 + lrow;
    if (ar < M && ka < K) {
      av = (ka < splitK) ? *(const float4*)&A[(size_t)ar * lda + ka]
                         : *(const float4*)&A2[(size_t)ar * lda2 + (ka - splitK)];
    }
    float4 bv = make_float4(0.f, 0.f, 0.f, 0.f);
    int br = col0 + lrow;
    if (br < N && ka < K) bv = *(const float4*)&B[(size_t)br * ldb + ka];
    __syncthreads();
    As[lk + 0][lrow] = av.x; As[lk + 1][lrow] = av.y;
    As[lk + 2][lrow] = av.z; As[lk + 3][lrow] = av.w;
    Bs[lk + 0][lrow] = bv.x; Bs[lk + 1][lrow] = bv.y;
    Bs[lk + 2][lrow] = bv.z; Bs[lk + 3][lrow] = bv.w;
    __syncthreads();
#pragma unroll
    for (int kk = 0; kk < 16; kk++) {
      const float4 a4 = *(const float4*)&As[kk][tm << 2];
      const float4 b4 = *(const float4*)&Bs[kk][tn << 2];
      float aa[4] = {a4.x, a4.y, a4.z, a4.w};
      float bb[4] = {b4.x, b4.y, b4.z, b4.w};
#pragma unroll
      for (int i = 0; i < 4; i++)
#pragma unroll
        for (int j = 0; j < 4; j++) acc[i][j] += aa[i] * bb[j];
    }
  }
  int rbase = row0 + (tm << 2), cbase = col0 + (tn << 2);
#pragma unroll
  for (int i = 0; i < 4; i++) {
    int r = rbase + i;
    if (r >= M) continue;
#pragma unroll
    for (int j = 0; j < 4; j++) {
      int c = cbase + j;
      if (c >= N) continue;
      float v = acc[i][j];
      if (bias) v += bias[c];
      if (relu && v < 0.f) v = 0.f;
      C[(size_t)r * ldc + c] = v;
    }
  }
}

// per-row: scores -> softmax -> input-space aggregation. UY in/out [rows][520]
__global__ __launch_bounds__(256) void k_score(
    float* __restrict__ UY,
    const float* __restrict__ feat,   // [rows][20][128]
    const float* __restrict__ tsrc,   // [rows]
    const float* __restrict__ tngh,   // [rows][20]
    const int*   __restrict__ idx,    // [rows][20]
    const float* __restrict__ freq, const float* __restrict__ phase,
    int rows)
{
  __shared__ __align__(16) float Ush[520];
  __shared__ __align__(16) float fsh[20][128];
  __shared__ __align__(16) float tesh[20][128];
  __shared__ float ssh[2][20];
  __shared__ float ash[2][20];
  __shared__ float dtsh[20];
  __shared__ int msh[20];
  int row = blockIdx.x;
  if (row >= rows) return;
  int tid = threadIdx.x;
  for (int u = tid; u < 520; u += 256) Ush[u] = UY[(size_t)row * 520 + u];
  const float4* fg = (const float4*)(feat + (size_t)row * 20 * 128);
  float4* fs4 = (float4*)&fsh[0][0];
  for (int i = tid; i < 640; i += 256) fs4[i] = fg[i];
  if (tid < 20) {
    dtsh[tid] = tsrc[row] - tngh[(size_t)row * 20 + tid];
    msh[tid] = (idx[(size_t)row * 20 + tid] == 0);
  }
  __syncthreads();
  for (int i = tid; i < 2560; i += 256) {
    int j = i >> 7, t = i & 127;
    tesh[j][t] = cosf(dtsh[j] * freq[t] + phase[t]);
  }
  __syncthreads();
  int wave = tid >> 6, lane = tid & 63;
  for (int p = wave; p < 40; p += 4) {
    int h = p / 20, j = p % 20;
    float4 u4 = *(const float4*)&Ush[h * 260 + (lane << 2)];
    float4 x4;
    if (lane < 32) x4 = *(const float4*)&fsh[j][lane << 2];
    else x4 = *(const float4*)&tesh[j][(lane - 32) << 2];
    float part = u4.x * x4.x + u4.y * x4.y + u4.z * x4.z + u4.w * x4.w;
    for (int m = 32; m; m >>= 1) part += __shfl_xor(part, m, 64);
    if (lane == 0) ssh[h][j] = part + Ush[h * 260 + 256];
  }
  __syncthreads();
  if (tid < 2) {
    const float scale = 0.08838834764831845f; // 1/sqrt(128)
    float sc[20];
    float mx = -3.0e38f;
    for (int j = 0; j < 20; j++) {
      float s = msh[j] ? -1e10f : ssh[tid][j] * scale;
      sc[j] = s; if (s > mx) mx = s;
    }
    float sum = 0.f;
    for (int j = 0; j < 20; j++) { float e = expf(sc[j] - mx); sc[j] = e; sum += e; }
    float inv = 1.0f / sum;
    for (int j = 0; j < 20; j++) ash[tid][j] = sc[j] * inv;
  }
  __syncthreads();
  float* Yrow = UY + (size_t)row * 520;
#pragma unroll
  for (int rep = 0; rep < 2; rep++) {
    int h = rep, e = tid;
    float acc = 0.f;
    if (e < 128) { for (int j = 0; j < 20; j++) acc += ash[h][j] * fsh[j][e]; }
    else { int t = e - 128; for (int j = 0; j < 20; j++) acc += ash[h][j] * tesh[j][t]; }
    Yrow[h * 260 + e] = acc;
  }
  if (tid < 4) {
    Yrow[256 + tid] = (tid == 0) ? 1.f : 0.f;
    Yrow[516 + tid] = (tid == 0) ? 1.f : 0.f;
  }
}

// fcb + residual(q=[src,te0]) + LayerNorm, in place on P [rows][256]
__global__ __launch_bounds__(256) void k_ln(
    float* __restrict__ P, const float* __restrict__ fcb,
    const float* __restrict__ srcv, const float* __restrict__ te0,
    const float* __restrict__ g, const float* __restrict__ b, int rows)
{
  int wave = threadIdx.x >> 6, lane = threadIdx.x & 63;
  int row = blockIdx.x * 4 + wave;
  if (row >= rows) return;
  float4 v = *(float4*)&P[(size_t)row * 256 + (lane << 2)];
  float4 fb = *(const float4*)&fcb[lane << 2];
  float4 q;
  if (lane < 32) q = *(const float4*)&srcv[(size_t)row * 128 + (lane << 2)];
  else q = *(const float4*)&te0[(lane - 32) << 2];
  v.x += fb.x + q.x; v.y += fb.y + q.y; v.z += fb.z + q.z; v.w += fb.w + q.w;
  float s = v.x + v.y + v.z + v.w;
  for (int m = 32; m; m >>= 1) s += __shfl_xor(s, m, 64);
  float mean = s * (1.0f / 256.0f);
  float d0 = v.x - mean, d1 = v.y - mean, d2 = v.z - mean, d3 = v.w - mean;
  float vs = d0 * d0 + d1 * d1 + d2 * d2 + d3 * d3;
  for (int m = 32; m; m >>= 1) vs += __shfl_xor(vs, m, 64);
  float rstd = rsqrtf(vs * (1.0f / 256.0f) + 1e-5f);
  float4 gg = *(const float4*)&g[lane << 2];
  float4 bb = *(const float4*)&b[lane << 2];
  float4 o;
  o.x = d0 * rstd * gg.x + bb.x; o.y = d1 * rstd * gg.y + bb.y;
  o.z = d2 * rstd * gg.z + bb.z; o.w = d3 * rstd * gg.w + bb.w;
  *(float4*)&P[(size_t)row * 256 + (lane << 2)] = o;
}

__global__ __launch_bounds__(256) void k_transpose(
    const float* __restrict__ src, float* __restrict__ dst, int R, int C)
{
  int idx = blockIdx.x * 256 + threadIdx.x;
  if (idx >= R * C) return;
  int c = idx / R, r = idx % R;
  dst[idx] = src[(size_t)r * C + c];
}

__global__ __launch_bounds__(256) void k_loss(
    const float* __restrict__ z, const float* __restrict__ adj, float* __restrict__ acc)
{
  __shared__ __align__(16) float zi[64][128];
  __shared__ __align__(16) float zj[64][128];
  int bi = blockIdx.x, bj = blockIdx.y;
  int tid = threadIdx.x;
  const float4* zig = (const float4*)(z + (size_t)bi * 64 * 128);
  const float4* zjg = (const float4*)(z + (size_t)bj * 64 * 128);
  float4* zis = (float4*)&zi[0][0];
  float4* zjs = (float4*)&zj[0][0];
  for (int i = tid; i < 2048; i += 256) { zis[i] = zig[i]; zjs[i] = zjg[i]; }
  __syncthreads();
  int ti = tid >> 4, tj = tid & 15;
  float dacc[4][4] = {{0.f}};
  for (int k = 0; k < 128; k += 4) {
    float4 a[4], b[4];
#pragma unroll
    for (int ii = 0; ii < 4; ii++) a[ii] = *(const float4*)&zi[ti * 4 + ii][k];
#pragma unroll
    for (int jj = 0; jj < 4; jj++) b[jj] = *(const float4*)&zj[tj * 4 + jj][k];
#pragma unroll
    for (int ii = 0; ii < 4; ii++)
#pragma unroll
      for (int jj = 0; jj < 4; jj++)
        dacc[ii][jj] += a[ii].x * b[jj].x + a[ii].y * b[jj].y + a[ii].z * b[jj].z + a[ii].w * b[jj].w;
  }
  float lsum = 0.f;
#pragma unroll
  for (int ii = 0; ii < 4; ii++) {
    int gi = bi * 64 + ti * 4 + ii;
    float4 ad = *(const float4*)&adj[(size_t)gi * 4096 + bj * 64 + tj * 4];
    float av[4] = {ad.x, ad.y, ad.z, ad.w};
#pragma unroll
    for (int jj = 0; jj < 4; jj++) {
      float sgm = 1.0f / (1.0f + expf(-dacc[ii][jj]));
      float d = av[jj] - sgm;
      lsum += d * d;
    }
  }
  for (int m = 32; m; m >>= 1) lsum += __shfl_xor(lsum, m, 64);
  __shared__ float wsum[4];
  if ((tid & 63) == 0) wsum[tid >> 6] = lsum;
  __syncthreads();
  if (tid == 0) atomicAdd(acc, wsum[0] + wsum[1] + wsum[2] + wsum[3]);
}

__global__ void k_zero(float* p) { p[0] = 0.f; }
__global__ void k_final(const float* acc, float* out) {
  out[0] = acc[0] * (1.0f / (4096.0f * 4096.0f));
}

extern "C" void kernel_launch(void* const* d_in, const int* in_sizes, int n_in,
                              void* d_out, int out_size, void* d_ws, size_t ws_size,
                              hipStream_t stream) {
  const float* src_feat  = (const float*)d_in[0];
  const float* src_t     = (const float*)d_in[1];
  const int*   ngh1_idx  = (const int*)d_in[2];
  const float* ngh1_t    = (const float*)d_in[3];
  const float* ngh1_feat = (const float*)d_in[4];
  const int*   ngh2_idx  = (const int*)d_in[5];
  const float* ngh2_t    = (const float*)d_in[6];
  const float* ngh2_feat = (const float*)d_in[7];
  const float* ae_x      = (const float*)d_in[8];
  const float* ae_adj    = (const float*)d_in[9];
  const float* W_lin     = (const float*)d_in[10];
  const float* b_lin     = (const float*)d_in[11];
  const float* freq      = (const float*)d_in[12];
  const float* phase     = (const float*)d_in[13];
  const float* wq        = (const float*)d_in[14];
  const float* wk        = (const float*)d_in[15];
  const float* wv        = (const float*)d_in[16];
  const float* fcw       = (const float*)d_in[17];
  const float* fcb       = (const float*)d_in[18];
  const float* lng       = (const float*)d_in[19];
  const float* lnb       = (const float*)d_in[20];
  const float* m1w       = (const float*)d_in[21];
  const float* m1b       = (const float*)d_in[22];
  const float* m2w       = (const float*)d_in[23];
  const float* m2b       = (const float*)d_in[24];
  const float* W_gc      = (const float*)d_in[25];
  const float* b_gc      = (const float*)d_in[26];
  float* out = (float*)d_out;

  const int NB = 2048, NA = 40960;  // batch, batch*K

  char* w = (char*)d_ws;
  size_t off = 0;
  auto alloc = [&](size_t bytes) -> float* {
    float* p = (float*)(w + off);
    off += (bytes + 255) & ~(size_t)255;
    return p;
  };
  float* te0    = alloc(128 * 4);
  float* linS   = alloc((size_t)NB * 128 * 4);
  float* lin1   = alloc((size_t)NA * 128 * 4);
  float* src_l1 = alloc((size_t)NB * 128 * 4);
  float* ngh_l1 = alloc((size_t)NA * 128 * 4);
  float* bq     = alloc(2 * 256 * 4);
  float* Mb     = alloc((size_t)2 * 2 * 256 * 128 * 4);
  float* cbf    = alloc(2 * 2 * 256 * 4);
  float* SW     = alloc((size_t)3 * 520 * 128 * 4);
  float* cbU    = alloc(3 * 520 * 4);
  float* OW     = alloc((size_t)3 * 2 * 128 * 260 * 4);
  float* F      = alloc((size_t)3 * 256 * 520 * 4);
  float* WgcT   = alloc(128 * 128 * 4);
  float* xw     = alloc((size_t)4096 * 128 * 4);
  float* xwT    = alloc((size_t)4096 * 128 * 4);
  float* zb     = alloc((size_t)4096 * 128 * 4);
  float* lacc   = alloc(256);
  size_t fixed = off;

  size_t avail = (ws_size > fixed) ? (ws_size - fixed) : 0;
  long rows_c = (long)(avail / 3720);  // (520+256+128)*4 + align margin
  if (rows_c > NA) rows_c = NA;
  rows_c &= ~63L;
  if (rows_c < 2048) rows_c = 2048;
  float* Ubuf  = alloc((size_t)rows_c * 520 * 4);
  float* Pbuf  = alloc((size_t)rows_c * 256 * 4);
  float* H1buf = alloc((size_t)rows_c * 128 * 4);

  auto gemm = [&](const float* A, const float* A2, int splitK, int lda, int lda2,
                  const float* Bm, int ldb, const float* bias, float* Cm, int ldc,
                  int M, int N, int Kd, int relu) {
    dim3 g((M + 63) / 64, (N + 63) / 64);
    k_gemm64<<<g, 256, 0, stream>>>(A, A2, splitK, lda, lda2, Bm, ldb, bias, Cm, ldc, M, N, Kd, relu);
  };
  const int BIG = 1 << 30;

  // ---- folded weights ----
  k_te0<<<1, 128, 0, stream>>>(phase, te0);
  for (int l = 0; l < 2; l++) {
    const float* wq_l = wq + (size_t)l * 256 * 256;
    const float* wk_l = wk + (size_t)l * 256 * 256;
    // bq[o] = sum_t wq[o][128+t] * te0[t]
    k_sgemm_naive<<<1, 256, 0, stream>>>(wq_l + 128, te0, bq + l * 256,
                                         256, 1, 128, 256, 1, 1, 0);
    for (int h = 0; h < 2; h++) {
      // M_h[e][s] = sum_d wk[h*128+d][e] * wq[h*128+d][s]
      k_sgemm_naive<<<(256 * 128 + 255) / 256, 256, 0, stream>>>(
          wk_l + (size_t)h * 128 * 256, wq_l + (size_t)h * 128 * 256,
          Mb + ((size_t)l * 2 + h) * 256 * 128, 256, 128, 128, 256, 256, 128, 1);
      // c_h[e] = sum_d wk[h*128+d][e] * bq[h*128+d]
      k_sgemm_naive<<<1, 256, 0, stream>>>(
          wk_l + (size_t)h * 128 * 256, bq + l * 256 + h * 128,
          cbf + ((size_t)l * 2 + h) * 256, 256, 1, 128, 256, 1, 1, 1);
    }
  }
  const int callLayer[3] = {0, 0, 1};
  const int callLin[3]   = {1, 0, 0};
  for (int ci = 0; ci < 3; ci++) {
    int l = callLayer[ci], ul = callLin[ci];
    k_build_SW<<<(520 * 128 + 255) / 256, 256, 0, stream>>>(
        SW + (size_t)ci * 520 * 128, cbU + ci * 520,
        Mb + (size_t)l * 2 * 256 * 128, cbf + (size_t)l * 2 * 256, W_lin, b_lin, ul);
    k_build_OW<<<(2 * 128 * 260 + 255) / 256, 256, 0, stream>>>(
        OW + (size_t)ci * 2 * 128 * 260, wv + (size_t)l * 256 * 256, W_lin, b_lin, ul);
    for (int h = 0; h < 2; h++) {
      // F[p][h*260+u] = sum_d fcw[p][h*128+d] * OW[h][d][u]
      k_sgemm_naive<<<(256 * 260 + 255) / 256, 256, 0, stream>>>(
          fcw + (size_t)l * 256 * 256 + h * 128,
          OW + (size_t)ci * 2 * 128 * 260 + (size_t)h * 128 * 260,
          F + (size_t)ci * 256 * 520 + h * 260,
          256, 260, 128, 256, 260, 520, 0);
    }
  }

  // ---- feature linear layers ----
  gemm(src_feat, src_feat, BIG, 128, 128, W_lin, 128, b_lin, linS, 128, NB, 128, 128, 0);
  gemm(ngh1_feat, ngh1_feat, BIG, 128, 128, W_lin, 128, b_lin, lin1, 128, NA, 128, 128, 0);

  // ---- attention calls ----
  auto attn_call = [&](int ci, long rows_total, const float* srcvec,
                       const float* featp, const float* tsrcp, const float* tnghp,
                       const int* idxp, int l, float* outp) {
    for (long r0 = 0; r0 < rows_total; r0 += rows_c) {
      long rem = rows_total - r0;
      int rows = (int)(rem < rows_c ? rem : rows_c);
      gemm(srcvec + r0 * 128, srcvec, BIG, 128, 128,
           SW + (size_t)ci * 520 * 128, 128, cbU + ci * 520, Ubuf, 520, rows, 520, 128, 0);
      k_score<<<rows, 256, 0, stream>>>(Ubuf, featp + r0 * 20 * 128, tsrcp + r0,
                                        tnghp + r0 * 20, idxp + r0 * 20, freq, phase, rows);
      gemm(Ubuf, Ubuf, BIG, 520, 520, F + (size_t)ci * 256 * 520, 520, nullptr,
           Pbuf, 256, rows, 256, 520, 0);
      k_ln<<<(rows + 3) / 4, 256, 0, stream>>>(Pbuf, fcb + l * 256, srcvec + r0 * 128,
                                               te0, lng + l * 256, lnb + l * 256, rows);
      gemm(Pbuf, srcvec + r0 * 128, 256, 256, 128, m1w + (size_t)l * 128 * 384, 384,
           m1b + l * 128, H1buf, 128, rows, 128, 384, 1);
      gemm(H1buf, H1buf, BIG, 128, 128, m2w + (size_t)l * 128 * 128, 128,
           m2b + l * 128, outp + r0 * 128, 128, rows, 128, 128, 0);
    }
  };
  // call A: neighbor-of-neighbor attention (layer0, raw ngh2 features, lin folded)
  attn_call(0, NA, lin1, ngh2_feat, ngh1_t, ngh2_t, ngh2_idx, 0, ngh_l1);
  // call B: src layer-1 embedding (layer0)
  attn_call(1, NB, linS, lin1, src_t, ngh1_t, ngh1_idx, 0, src_l1);
  // call C: top attention (layer1) -> final embedding into d_out
  attn_call(2, NB, src_l1, ngh_l1, src_t, ngh1_t, ngh1_idx, 1, out);

  // ---- autoencoder loss ----
  k_transpose<<<(128 * 128 + 255) / 256, 256, 0, stream>>>(W_gc, WgcT, 128, 128);
  gemm(ae_x, ae_x, BIG, 128, 128, WgcT, 128, nullptr, xw, 128, 4096, 128, 128, 0);
  k_transpose<<<(4096 * 128 + 255) / 256, 256, 0, stream>>>(xw, xwT, 4096, 128);
  gemm(ae_adj, ae_adj, BIG, 4096, 4096, xwT, 4096, b_gc, zb, 128, 4096, 128, 4096, 0);
  k_zero<<<1, 1, 0, stream>>>(lacc);
  k_loss<<<dim3(64, 64), 256, 0, stream>>>(zb, ae_adj, lacc);
  k_final<<<1, 1, 0, stream>>>(lacc, out + (size_t)NB * 128);
}

// Round 2
// 1237.123 us; speedup vs baseline: 1.6314x; 1.6314x over previous
//
#include <hip/hip_runtime.h>
#include <math.h>

// ---------------------------------------------------------------------------
// TGAT classifier. Same algebraic folding as round 1 (score/aggregate in input
// space, wq/wk/wv/W_lin/fc_w folded), but:
//  - all fat GEMMs now f16 MFMA (mfma_f32_16x16x32_f16, f32 accumulate)
//  - k_score uses __cosf, 16-lane dot groups, wave-parallel softmax
//  - setup folds batched into 6 launches
// ---------------------------------------------------------------------------

typedef _Float16 h4 __attribute__((ext_vector_type(4)));
typedef _Float16 h8 __attribute__((ext_vector_type(8)));
typedef float f4 __attribute__((ext_vector_type(4)));

// ---------------- setup fold kernels ----------------

__global__ __launch_bounds__(256) void k_prep1(
    const float* __restrict__ phase, const float* __restrict__ wq,
    float* __restrict__ te0, float* __restrict__ bq)
{
  int l = blockIdx.x, t = threadIdx.x;
  __shared__ float te[128];
  if (t < 128) te[t] = cosf(phase[t]);
  __syncthreads();
  if (l == 0 && t < 128) te0[t] = te[t];
  const float* wr = wq + ((size_t)l * 256 + t) * 256 + 128;
  float s = 0.f;
  for (int k = 0; k < 128; k++) s += wr[k] * te[k];
  bq[l * 256 + t] = s;
}

__global__ __launch_bounds__(256) void k_prep2(
    const float* __restrict__ wk, const float* __restrict__ bq, float* __restrict__ cbf)
{
  int lh = blockIdx.x, l = lh >> 1, h = lh & 1, e = threadIdx.x;
  const float* wkb = wk + (size_t)l * 65536 + (size_t)h * 128 * 256;
  const float* bqb = bq + l * 256 + h * 128;
  float s = 0.f;
  for (int d = 0; d < 128; d++) s += wkb[(size_t)d * 256 + e] * bqb[d];
  cbf[lh * 256 + e] = s;
}

__global__ __launch_bounds__(256) void k_prepM(
    const float* __restrict__ wq, const float* __restrict__ wk, float* __restrict__ Mb)
{
  int lh = blockIdx.y, l = lh >> 1, h = lh & 1;
  int idx = blockIdx.x * 256 + threadIdx.x;   // < 256*128
  int e = idx >> 7, s = idx & 127;
  const float* wkb = wk + (size_t)l * 65536 + (size_t)h * 128 * 256;
  const float* wqb = wq + (size_t)l * 65536 + (size_t)h * 128 * 256;
  float acc = 0.f;
  for (int d = 0; d < 128; d++) acc += wkb[(size_t)d * 256 + e] * wqb[(size_t)d * 256 + s];
  Mb[(size_t)lh * 32768 + idx] = acc;
}

__global__ __launch_bounds__(256) void k_build_SW(
    float* __restrict__ SWa, float* __restrict__ cba,
    const float* __restrict__ Mb, const float* __restrict__ cbf,
    const float* __restrict__ Wlin, const float* __restrict__ blin)
{
  int ci = blockIdx.y;
  int lyr = (ci == 2) ? 1 : 0;
  int ul  = (ci == 0) ? 1 : 0;
  const float* M2 = Mb + (size_t)lyr * 2 * 32768;
  const float* c2 = cbf + (size_t)lyr * 512;
  float* SW = SWa + (size_t)ci * 520 * 128;
  float* cb = cba + (size_t)ci * 520;
  int idx = blockIdx.x * 256 + threadIdx.x;
  if (idx >= 520 * 128) return;
  int urow = idx / 128, s = idx % 128;
  int h = urow / 260, u = urow % 260;
  const float* M = M2 + (size_t)h * 32768;
  const float* c = c2 + h * 256;
  float val = 0.f, cbv = 0.f;
  if (u < 128) {
    if (ul) {
      for (int cc = 0; cc < 128; cc++) {
        float w = Wlin[cc * 128 + u];
        val += w * M[cc * 128 + s];
        cbv += w * c[cc];
      }
    } else { val = M[u * 128 + s]; cbv = c[u]; }
  } else if (u < 256) {
    val = M[u * 128 + s]; cbv = c[u];
  } else if (u == 256) {
    if (ul) {
      for (int cc = 0; cc < 128; cc++) {
        float w = blin[cc];
        val += w * M[cc * 128 + s];
        cbv += w * c[cc];
      }
    }
  }
  SW[(size_t)urow * 128 + s] = val;
  if (s == 0) cb[urow] = cbv;
}

__global__ __launch_bounds__(256) void k_build_OW(
    float* __restrict__ OWa, const float* __restrict__ wv,
    const float* __restrict__ Wlin, const float* __restrict__ blin)
{
  int ci = blockIdx.y;
  int lyr = (ci == 2) ? 1 : 0;
  int ul  = (ci == 0) ? 1 : 0;
  float* OW = OWa + (size_t)ci * 2 * 128 * 260;
  const float* wvl = wv + (size_t)lyr * 65536;
  int idx = blockIdx.x * 256 + threadIdx.x;
  if (idx >= 2 * 128 * 260) return;
  int u = idx % 260; int d = (idx / 260) % 128; int h = idx / (260 * 128);
  const float* wr = wvl + (size_t)(h * 128 + d) * 256;
  float val = 0.f;
  if (u < 128) {
    if (ul) { for (int cc = 0; cc < 128; cc++) val += wr[cc] * Wlin[cc * 128 + u]; }
    else val = wr[u];
  } else if (u < 256) {
    val = wr[u];
  } else if (u == 256) {
    if (ul) { for (int cc = 0; cc < 128; cc++) val += wr[cc] * blin[cc]; }
  }
  OW[idx] = val;
}

__global__ __launch_bounds__(256) void k_build_F(
    float* __restrict__ Fa, const float* __restrict__ fcw, const float* __restrict__ OWa)
{
  int ci = blockIdx.y >> 1, h = blockIdx.y & 1;
  int lyr = (ci == 2) ? 1 : 0;
  int idx = blockIdx.x * 256 + threadIdx.x;   // < 256*260
  int p = idx / 260, u = idx % 260;
  const float* fw = fcw + (size_t)lyr * 65536 + (size_t)p * 256 + h * 128;
  const float* ow = OWa + (size_t)ci * 2 * 128 * 260 + (size_t)h * 128 * 260;
  float s = 0.f;
  for (int d = 0; d < 128; d++) s += fw[d] * ow[(size_t)d * 260 + u];
  Fa[(size_t)ci * 256 * 520 + (size_t)p * 520 + h * 260 + u] = s;
}

// ---------------- f16 MFMA GEMM: C[M,N] = Acat[M,K] @ B[N,K].T (+bias)(+relu)
// Acat col k: k<splitK -> A[r*lda+k] else A2[r*lda2+k-splitK]. M % BM == 0.

template<int BM, int BN>
__global__ __launch_bounds__(256) void k_mgemm(
    const float* __restrict__ A, const float* __restrict__ A2, int splitK,
    int lda, int lda2,
    const float* __restrict__ B, int ldb,
    const float* __restrict__ bias,
    float* __restrict__ C, int ldc,
    int M, int N, int K, int relu)
{
  constexpr int BK = 64;
  constexpr int LDS = BK + 8;
  __shared__ _Float16 As[BM][LDS];
  __shared__ _Float16 Bs[BN][LDS];
  constexpr int FM = BM / 32;
  constexpr int FN = BN / 32;
  int tid = threadIdx.x;
  int wv = tid >> 6, lane = tid & 63;
  int wm = wv >> 1, wn = wv & 1;
  int row0 = blockIdx.x * BM, col0 = blockIdx.y * BN;
  int m0 = wm * (BM / 2), n0 = wn * (BN / 2);
  int lr = lane & 15, lk = lane >> 4;

  f4 acc[FM][FN];
#pragma unroll
  for (int i = 0; i < FM; i++)
#pragma unroll
    for (int j = 0; j < FN; j++) acc[i][j] = (f4)0.f;

  constexpr int TPRA = 256 / BM;
  constexpr int F4A = (BK / TPRA) / 4;
  int arow = tid / TPRA;
  int acol = (tid % TPRA) * (BK / TPRA);
  constexpr int TPRB = 256 / BN;
  constexpr int F4B = (BK / TPRB) / 4;
  int brow = tid / TPRB;
  int bcol = (tid % TPRB) * (BK / TPRB);
  int gar = row0 + arow;
  int gbr = col0 + brow;
  bool bvalid = gbr < N;

  for (int k0 = 0; k0 < K; k0 += BK) {
    __syncthreads();
#pragma unroll
    for (int j = 0; j < F4A; j++) {
      int ka = k0 + acol + j * 4;
      f4 v = (f4)0.f;
      if (ka < K) {
        const float* src = (ka < splitK) ? &A[(size_t)gar * lda + ka]
                                         : &A2[(size_t)gar * lda2 + (ka - splitK)];
        v = *(const f4*)src;
      }
      h4 hv = { (_Float16)v.x, (_Float16)v.y, (_Float16)v.z, (_Float16)v.w };
      *(h4*)&As[arow][acol + j * 4] = hv;
    }
#pragma unroll
    for (int j = 0; j < F4B; j++) {
      int ka = k0 + bcol + j * 4;
      f4 v = (f4)0.f;
      if (bvalid && ka < K) v = *(const f4*)&B[(size_t)gbr * ldb + ka];
      h4 hv = { (_Float16)v.x, (_Float16)v.y, (_Float16)v.z, (_Float16)v.w };
      *(h4*)&Bs[brow][bcol + j * 4] = hv;
    }
    __syncthreads();
#pragma unroll
    for (int kk = 0; kk < 2; kk++) {
      h8 af[FM], bf[FN];
#pragma unroll
      for (int i = 0; i < FM; i++)
        af[i] = *(h8*)&As[m0 + i * 16 + lr][kk * 32 + lk * 8];
#pragma unroll
      for (int j = 0; j < FN; j++)
        bf[j] = *(h8*)&Bs[n0 + j * 16 + lr][kk * 32 + lk * 8];
#pragma unroll
      for (int i = 0; i < FM; i++)
#pragma unroll
        for (int j = 0; j < FN; j++)
          acc[i][j] = __builtin_amdgcn_mfma_f32_16x16x32_f16(af[i], bf[j], acc[i][j], 0, 0, 0);
    }
  }
#pragma unroll
  for (int j = 0; j < FN; j++) {
    int c = col0 + n0 + j * 16 + lr;
    if (c >= N) continue;
    float bz = bias ? bias[c] : 0.f;
#pragma unroll
    for (int i = 0; i < FM; i++) {
      int rbase = row0 + m0 + i * 16 + lk * 4;
#pragma unroll
      for (int r = 0; r < 4; r++) {
        int rr = rbase + r;
        if (rr >= M) continue;
        float v = acc[i][j][r] + bz;
        if (relu && v < 0.f) v = 0.f;
        C[(size_t)rr * ldc + c] = v;
      }
    }
  }
}

// ---------------- per-row score/softmax/aggregate (in place on UY) ----------

__global__ __launch_bounds__(256) void k_score(
    float* __restrict__ UY,
    const float* __restrict__ feat,   // [rows][20][128]
    const float* __restrict__ tsrc,   // [rows]
    const float* __restrict__ tngh,   // [rows][20]
    const int*   __restrict__ idx,    // [rows][20]
    const float* __restrict__ freq, const float* __restrict__ phase,
    int rows)
{
  __shared__ __align__(16) float Ush[520];
  __shared__ __align__(16) float fsh[20][132];
  __shared__ __align__(16) float tesh[20][132];
  __shared__ __align__(16) float fq[128];
  __shared__ __align__(16) float ph[128];
  __shared__ float ssh[2][20];
  __shared__ float ash[2][20];
  __shared__ float dtsh[20];
  __shared__ int msh[20];
  int row = blockIdx.x;
  if (row >= rows) return;
  int tid = threadIdx.x;
  for (int u = tid; u < 520; u += 256) Ush[u] = UY[(size_t)row * 520 + u];
  if (tid < 128) { fq[tid] = freq[tid]; ph[tid] = phase[tid]; }
  const float4* fg = (const float4*)(feat + (size_t)row * 20 * 128);
  for (int i = tid; i < 640; i += 256) {
    int j = i >> 5, c4 = i & 31;
    *(float4*)&fsh[j][c4 * 4] = fg[i];
  }
  if (tid < 20) {
    dtsh[tid] = tsrc[row] - tngh[(size_t)row * 20 + tid];
    msh[tid] = (idx[(size_t)row * 20 + tid] == 0);
  }
  __syncthreads();
  for (int i = tid; i < 2560; i += 256) {
    int j = i >> 7, t = i & 127;
    tesh[j][t] = __cosf(dtsh[j] * fq[t] + ph[t]);
  }
  __syncthreads();
  // scores: 16-lane groups, p = head*20 + j
  int wv = tid >> 6, lane = tid & 63;
  int grp = lane >> 4, li = lane & 15;
#pragma unroll
  for (int it = 0; it < 3; it++) {
    int p = it * 16 + wv * 4 + grp;
    float part = 0.f;
    int h = (p < 40) ? (p / 20) : 0;
    int j = (p < 40) ? (p - h * 20) : 0;
    if (p < 40) {
      const float* urow = Ush + h * 260;
#pragma unroll
      for (int k = 0; k < 4; k++) {
        int e = li * 4 + k * 64;
        float4 u4 = *(const float4*)&urow[e];
        float4 x4 = (e < 128) ? *(const float4*)&fsh[j][e]
                              : *(const float4*)&tesh[j][e - 128];
        part += u4.x * x4.x + u4.y * x4.y + u4.z * x4.z + u4.w * x4.w;
      }
    }
    for (int m = 8; m; m >>= 1) part += __shfl_xor(part, m, 16);
    if (p < 40 && li == 0) ssh[h][j] = part + Ush[h * 260 + 256];
  }
  __syncthreads();
  // wave-parallel softmax: wave 0 -> head 0, wave 1 -> head 1
  if (wv < 2 && lane < 32) {
    const float scale = 0.08838834764831845f; // 1/sqrt(128)
    float s = (lane < 20) ? (msh[lane] ? -1e10f : ssh[wv][lane] * scale) : -3.0e38f;
    float mx = s;
    for (int m = 16; m; m >>= 1) mx = fmaxf(mx, __shfl_xor(mx, m, 32));
    float e = (lane < 20) ? __expf(s - mx) : 0.f;
    float sum = e;
    for (int m = 16; m; m >>= 1) sum += __shfl_xor(sum, m, 32);
    if (lane < 20) ash[wv][lane] = e / sum;
  }
  __syncthreads();
  // aggregate
  float* Yrow = UY + (size_t)row * 520;
  {
    float a0 = 0.f, a1 = 0.f;
    if (tid < 128) {
#pragma unroll 5
      for (int j = 0; j < 20; j++) {
        float x = fsh[j][tid];
        a0 += ash[0][j] * x; a1 += ash[1][j] * x;
      }
    } else if (tid < 256) {
      int t2 = tid - 128;
#pragma unroll 5
      for (int j = 0; j < 20; j++) {
        float x = tesh[j][t2];
        a0 += ash[0][j] * x; a1 += ash[1][j] * x;
      }
    }
    Yrow[tid] = a0;
    Yrow[260 + tid] = a1;
  }
  if (tid < 4) {
    Yrow[256 + tid] = (tid == 0) ? 1.f : 0.f;
    Yrow[516 + tid] = (tid == 0) ? 1.f : 0.f;
  }
}

// ---------------- residual + LayerNorm ----------------

__global__ __launch_bounds__(256) void k_ln(
    float* __restrict__ P, const float* __restrict__ fcb,
    const float* __restrict__ srcv, const float* __restrict__ te0,
    const float* __restrict__ g, const float* __restrict__ b, int rows)
{
  int wave = threadIdx.x >> 6, lane = threadIdx.x & 63;
  int row = blockIdx.x * 4 + wave;
  if (row >= rows) return;
  float4 v = *(float4*)&P[(size_t)row * 256 + (lane << 2)];
  float4 fb = *(const float4*)&fcb[lane << 2];
  float4 q;
  if (lane < 32) q = *(const float4*)&srcv[(size_t)row * 128 + (lane << 2)];
  else q = *(const float4*)&te0[(lane - 32) << 2];
  v.x += fb.x + q.x; v.y += fb.y + q.y; v.z += fb.z + q.z; v.w += fb.w + q.w;
  float s = v.x + v.y + v.z + v.w;
  for (int m = 32; m; m >>= 1) s += __shfl_xor(s, m, 64);
  float mean = s * (1.0f / 256.0f);
  float d0 = v.x - mean, d1 = v.y - mean, d2 = v.z - mean, d3 = v.w - mean;
  float vs = d0 * d0 + d1 * d1 + d2 * d2 + d3 * d3;
  for (int m = 32; m; m >>= 1) vs += __shfl_xor(vs, m, 64);
  float rstd = rsqrtf(vs * (1.0f / 256.0f) + 1e-5f);
  float4 gg = *(const float4*)&g[lane << 2];
  float4 bb = *(const float4*)&b[lane << 2];
  float4 o;
  o.x = d0 * rstd * gg.x + bb.x; o.y = d1 * rstd * gg.y + bb.y;
  o.z = d2 * rstd * gg.z + bb.z; o.w = d3 * rstd * gg.w + bb.w;
  *(float4*)&P[(size_t)row * 256 + (lane << 2)] = o;
}

__global__ __launch_bounds__(256) void k_transpose(
    const float* __restrict__ src, float* __restrict__ dst, int R, int C)
{
  int idx = blockIdx.x * 256 + threadIdx.x;
  if (idx >= R * C) return;
  int c = idx / R, r = idx % R;
  dst[idx] = src[(size_t)r * C + c];
}

__global__ __launch_bounds__(256) void k_loss(
    const float* __restrict__ z, const float* __restrict__ adj, float* __restrict__ acc)
{
  __shared__ __align__(16) float zi[64][128];
  __shared__ __align__(16) float zj[64][128];
  int bi = blockIdx.x, bj = blockIdx.y;
  int tid = threadIdx.x;
  const float4* zig = (const float4*)(z + (size_t)bi * 64 * 128);
  const float4* zjg = (const float4*)(z + (size_t)bj * 64 * 128);
  float4* zis = (float4*)&zi[0][0];
  float4* zjs = (float4*)&zj[0][0];
  for (int i = tid; i < 2048; i += 256) { zis[i] = zig[i]; zjs[i] = zjg[i]; }
  __syncthreads();
  int ti = tid >> 4, tj = tid & 15;
  float dacc[4][4] = {{0.f}};
  for (int k = 0; k < 128; k += 4) {
    float4 a[4], b[4];
#pragma unroll
    for (int ii = 0; ii < 4; ii++) a[ii] = *(const float4*)&zi[ti * 4 + ii][k];
#pragma unroll
    for (int jj = 0; jj < 4; jj++) b[jj] = *(const float4*)&zj[tj * 4 + jj][k];
#pragma unroll
    for (int ii = 0; ii < 4; ii++)
#pragma unroll
      for (int jj = 0; jj < 4; jj++)
        dacc[ii][jj] += a[ii].x * b[jj].x + a[ii].y * b[jj].y + a[ii].z * b[jj].z + a[ii].w * b[jj].w;
  }
  float lsum = 0.f;
#pragma unroll
  for (int ii = 0; ii < 4; ii++) {
    int gi = bi * 64 + ti * 4 + ii;
    float4 ad = *(const float4*)&adj[(size_t)gi * 4096 + bj * 64 + tj * 4];
    float av[4] = {ad.x, ad.y, ad.z, ad.w};
#pragma unroll
    for (int jj = 0; jj < 4; jj++) {
      float sgm = 1.0f / (1.0f + __expf(-dacc[ii][jj]));
      float d = av[jj] - sgm;
      lsum += d * d;
    }
  }
  for (int m = 32; m; m >>= 1) lsum += __shfl_xor(lsum, m, 64);
  __shared__ float wsum[4];
  if ((tid & 63) == 0) wsum[tid >> 6] = lsum;
  __syncthreads();
  if (tid == 0) atomicAdd(acc, wsum[0] + wsum[1] + wsum[2] + wsum[3]);
}

__global__ void k_zero(float* p) { p[0] = 0.f; }
__global__ void k_final(const float* acc, float* out) {
  out[0] = acc[0] * (1.0f / (4096.0f * 4096.0f));
}

// ---------------------------------------------------------------------------

extern "C" void kernel_launch(void* const* d_in, const int* in_sizes, int n_in,
                              void* d_out, int out_size, void* d_ws, size_t ws_size,
                              hipStream_t stream) {
  const float* src_feat  = (const float*)d_in[0];
  const float* src_t     = (const float*)d_in[1];
  const int*   ngh1_idx  = (const int*)d_in[2];
  const float* ngh1_t    = (const float*)d_in[3];
  const float* ngh1_feat = (const float*)d_in[4];
  const int*   ngh2_idx  = (const int*)d_in[5];
  const float* ngh2_t    = (const float*)d_in[6];
  const float* ngh2_feat = (const float*)d_in[7];
  const float* ae_x      = (const float*)d_in[8];
  const float* ae_adj    = (const float*)d_in[9];
  const float* W_lin     = (const float*)d_in[10];
  const float* b_lin     = (const float*)d_in[11];
  const float* freq      = (const float*)d_in[12];
  const float* phase     = (const float*)d_in[13];
  const float* wq        = (const float*)d_in[14];
  const float* wk        = (const float*)d_in[15];
  const float* wv        = (const float*)d_in[16];
  const float* fcw       = (const float*)d_in[17];
  const float* fcb       = (const float*)d_in[18];
  const float* lng       = (const float*)d_in[19];
  const float* lnb       = (const float*)d_in[20];
  const float* m1w       = (const float*)d_in[21];
  const float* m1b       = (const float*)d_in[22];
  const float* m2w       = (const float*)d_in[23];
  const float* m2b       = (const float*)d_in[24];
  const float* W_gc      = (const float*)d_in[25];
  const float* b_gc      = (const float*)d_in[26];
  float* out = (float*)d_out;

  const int NB = 2048, NA = 40960;

  char* w = (char*)d_ws;
  size_t off = 0;
  auto alloc = [&](size_t bytes) -> float* {
    float* p = (float*)(w + off);
    off += (bytes + 255) & ~(size_t)255;
    return p;
  };
  float* te0    = alloc(128 * 4);
  float* linS   = alloc((size_t)NB * 128 * 4);
  float* lin1   = alloc((size_t)NA * 128 * 4);
  float* src_l1 = alloc((size_t)NB * 128 * 4);
  float* ngh_l1 = alloc((size_t)NA * 128 * 4);
  float* bq     = alloc(2 * 256 * 4);
  float* Mb     = alloc((size_t)2 * 2 * 256 * 128 * 4);
  float* cbf    = alloc(2 * 2 * 256 * 4);
  float* SW     = alloc((size_t)3 * 520 * 128 * 4);
  float* cbU    = alloc(3 * 520 * 4);
  float* OW     = alloc((size_t)3 * 2 * 128 * 260 * 4);
  float* F      = alloc((size_t)3 * 256 * 520 * 4);
  float* WgcT   = alloc(128 * 128 * 4);
  float* xw     = alloc((size_t)4096 * 128 * 4);
  float* xwT    = alloc((size_t)4096 * 128 * 4);
  float* zb     = alloc((size_t)4096 * 128 * 4);
  float* lacc   = alloc(256);
  size_t fixed = off;

  size_t avail = (ws_size > fixed) ? (ws_size - fixed) : 0;
  long rows_c = (long)(avail / 3720);
  if (rows_c > NA) rows_c = NA;
  rows_c &= ~127L;
  if (rows_c < 2048) rows_c = 2048;
  float* Ubuf  = alloc((size_t)rows_c * 520 * 4);
  float* Pbuf  = alloc((size_t)rows_c * 256 * 4);
  float* H1buf = alloc((size_t)rows_c * 128 * 4);

  auto gemm128 = [&](const float* A, const float* A2, int splitK, int lda, int lda2,
                     const float* Bm, int ldb, const float* bias, float* Cm, int ldc,
                     int M, int N, int Kd, int relu) {
    dim3 g(M / 128, (N + 127) / 128);
    k_mgemm<128, 128><<<g, 256, 0, stream>>>(A, A2, splitK, lda, lda2, Bm, ldb, bias,
                                             Cm, ldc, M, N, Kd, relu);
  };
  const int BIG = 1 << 30;

  // ---- folded weights (6 launches) ----
  k_prep1<<<2, 256, 0, stream>>>(phase, wq, te0, bq);
  k_prep2<<<4, 256, 0, stream>>>(wk, bq, cbf);
  k_prepM<<<dim3(128, 4), 256, 0, stream>>>(wq, wk, Mb);
  k_build_SW<<<dim3(260, 3), 256, 0, stream>>>(SW, cbU, Mb, cbf, W_lin, b_lin);
  k_build_OW<<<dim3(260, 3), 256, 0, stream>>>(OW, wv, W_lin, b_lin);
  k_build_F<<<dim3(260, 6), 256, 0, stream>>>(F, fcw, OW);

  // ---- feature linear layers ----
  gemm128(src_feat, src_feat, BIG, 128, 128, W_lin, 128, b_lin, linS, 128, NB, 128, 128, 0);
  gemm128(ngh1_feat, ngh1_feat, BIG, 128, 128, W_lin, 128, b_lin, lin1, 128, NA, 128, 128, 0);

  // ---- attention calls ----
  auto attn_call = [&](int ci, long rows_total, const float* srcvec,
                       const float* featp, const float* tsrcp, const float* tnghp,
                       const int* idxp, int l, float* outp) {
    for (long r0 = 0; r0 < rows_total; r0 += rows_c) {
      long rem = rows_total - r0;
      int rows = (int)(rem < rows_c ? rem : rows_c);
      gemm128(srcvec + r0 * 128, srcvec, BIG, 128, 128,
              SW + (size_t)ci * 520 * 128, 128, cbU + ci * 520, Ubuf, 520, rows, 520, 128, 0);
      k_score<<<rows, 256, 0, stream>>>(Ubuf, featp + r0 * 20 * 128, tsrcp + r0,
                                        tnghp + r0 * 20, idxp + r0 * 20, freq, phase, rows);
      gemm128(Ubuf, Ubuf, BIG, 520, 520, F + (size_t)ci * 256 * 520, 520, nullptr,
              Pbuf, 256, rows, 256, 520, 0);
      k_ln<<<(rows + 3) / 4, 256, 0, stream>>>(Pbuf, fcb + l * 256, srcvec + r0 * 128,
                                               te0, lng + l * 256, lnb + l * 256, rows);
      gemm128(Pbuf, srcvec + r0 * 128, 256, 256, 128, m1w + (size_t)l * 128 * 384, 384,
              m1b + l * 128, H1buf, 128, rows, 128, 384, 1);
      gemm128(H1buf, H1buf, BIG, 128, 128, m2w + (size_t)l * 128 * 128, 128,
              m2b + l * 128, outp + r0 * 128, 128, rows, 128, 128, 0);
    }
  };
  attn_call(0, NA, lin1, ngh2_feat, ngh1_t, ngh2_t, ngh2_idx, 0, ngh_l1);
  attn_call(1, NB, linS, lin1, src_t, ngh1_t, ngh1_idx, 0, src_l1);
  attn_call(2, NB, src_l1, ngh_l1, src_t, ngh1_t, ngh1_idx, 1, out);

  // ---- autoencoder loss ----
  k_transpose<<<(128 * 128 + 255) / 256, 256, 0, stream>>>(W_gc, WgcT, 128, 128);
  gemm128(ae_x, ae_x, BIG, 128, 128, WgcT, 128, nullptr, xw, 128, 4096, 128, 128, 0);
  k_transpose<<<(4096 * 128 + 255) / 256, 256, 0, stream>>>(xw, xwT, 4096, 128);
  {
    dim3 g(4096 / 64, 128 / 64);
    k_mgemm<64, 64><<<g, 256, 0, stream>>>(ae_adj, ae_adj, BIG, 4096, 4096, xwT, 4096,
                                           b_gc, zb, 128, 4096, 128, 4096, 0);
  }
  k_zero<<<1, 1, 0, stream>>>(lacc);
  k_loss<<<dim3(64, 64), 256, 0, stream>>>(zb, ae_adj, lacc);
  k_final<<<1, 1, 0, stream>>>(lacc, out + (size_t)NB * 128);
}

// Round 3
// 1084.649 us; speedup vs baseline: 1.8607x; 1.1406x over previous
//
#include <hip/hip_runtime.h>
#include <math.h>

// ---------------------------------------------------------------------------
// TGAT classifier. Algebraic folding (score/aggregate in input space,
// wq/wk/wv/W_lin/fc_w folded), f16 MFMA GEMMs, and now a fused MFMA
// autoencoder loss (z stored f16, fragments straight from L2, no LDS).
// ---------------------------------------------------------------------------

typedef _Float16 h4 __attribute__((ext_vector_type(4)));
typedef _Float16 h8 __attribute__((ext_vector_type(8)));
typedef float f4 __attribute__((ext_vector_type(4)));

// ---------------- setup fold kernels ----------------

__global__ __launch_bounds__(256) void k_prep1(
    const float* __restrict__ phase, const float* __restrict__ wq,
    float* __restrict__ te0, float* __restrict__ bq)
{
  int l = blockIdx.x, t = threadIdx.x;
  __shared__ float te[128];
  if (t < 128) te[t] = cosf(phase[t]);
  __syncthreads();
  if (l == 0 && t < 128) te0[t] = te[t];
  const float* wr = wq + ((size_t)l * 256 + t) * 256 + 128;
  float s = 0.f;
  for (int k = 0; k < 128; k++) s += wr[k] * te[k];
  bq[l * 256 + t] = s;
}

__global__ __launch_bounds__(256) void k_prep2(
    const float* __restrict__ wk, const float* __restrict__ bq, float* __restrict__ cbf)
{
  int lh = blockIdx.x, l = lh >> 1, h = lh & 1, e = threadIdx.x;
  const float* wkb = wk + (size_t)l * 65536 + (size_t)h * 128 * 256;
  const float* bqb = bq + l * 256 + h * 128;
  float s = 0.f;
  for (int d = 0; d < 128; d++) s += wkb[(size_t)d * 256 + e] * bqb[d];
  cbf[lh * 256 + e] = s;
}

__global__ __launch_bounds__(256) void k_prepM(
    const float* __restrict__ wq, const float* __restrict__ wk, float* __restrict__ Mb)
{
  int lh = blockIdx.y, l = lh >> 1, h = lh & 1;
  int idx = blockIdx.x * 256 + threadIdx.x;   // < 256*128
  int e = idx >> 7, s = idx & 127;
  const float* wkb = wk + (size_t)l * 65536 + (size_t)h * 128 * 256;
  const float* wqb = wq + (size_t)l * 65536 + (size_t)h * 128 * 256;
  float acc = 0.f;
  for (int d = 0; d < 128; d++) acc += wkb[(size_t)d * 256 + e] * wqb[(size_t)d * 256 + s];
  Mb[(size_t)lh * 32768 + idx] = acc;
}

__global__ __launch_bounds__(256) void k_build_SW(
    float* __restrict__ SWa, float* __restrict__ cba,
    const float* __restrict__ Mb, const float* __restrict__ cbf,
    const float* __restrict__ Wlin, const float* __restrict__ blin)
{
  int ci = blockIdx.y;
  int lyr = (ci == 2) ? 1 : 0;
  int ul  = (ci == 0) ? 1 : 0;
  const float* M2 = Mb + (size_t)lyr * 2 * 32768;
  const float* c2 = cbf + (size_t)lyr * 512;
  float* SW = SWa + (size_t)ci * 520 * 128;
  float* cb = cba + (size_t)ci * 520;
  int idx = blockIdx.x * 256 + threadIdx.x;
  if (idx >= 520 * 128) return;
  int urow = idx / 128, s = idx % 128;
  int h = urow / 260, u = urow % 260;
  const float* M = M2 + (size_t)h * 32768;
  const float* c = c2 + h * 256;
  float val = 0.f, cbv = 0.f;
  if (u < 128) {
    if (ul) {
      for (int cc = 0; cc < 128; cc++) {
        float w = Wlin[cc * 128 + u];
        val += w * M[cc * 128 + s];
        cbv += w * c[cc];
      }
    } else { val = M[u * 128 + s]; cbv = c[u]; }
  } else if (u < 256) {
    val = M[u * 128 + s]; cbv = c[u];
  } else if (u == 256) {
    if (ul) {
      for (int cc = 0; cc < 128; cc++) {
        float w = blin[cc];
        val += w * M[cc * 128 + s];
        cbv += w * c[cc];
      }
    }
  }
  SW[(size_t)urow * 128 + s] = val;
  if (s == 0) cb[urow] = cbv;
}

__global__ __launch_bounds__(256) void k_build_OW(
    float* __restrict__ OWa, const float* __restrict__ wv,
    const float* __restrict__ Wlin, const float* __restrict__ blin)
{
  int ci = blockIdx.y;
  int lyr = (ci == 2) ? 1 : 0;
  int ul  = (ci == 0) ? 1 : 0;
  float* OW = OWa + (size_t)ci * 2 * 128 * 260;
  const float* wvl = wv + (size_t)lyr * 65536;
  int idx = blockIdx.x * 256 + threadIdx.x;
  if (idx >= 2 * 128 * 260) return;
  int u = idx % 260; int d = (idx / 260) % 128; int h = idx / (260 * 128);
  const float* wr = wvl + (size_t)(h * 128 + d) * 256;
  float val = 0.f;
  if (u < 128) {
    if (ul) { for (int cc = 0; cc < 128; cc++) val += wr[cc] * Wlin[cc * 128 + u]; }
    else val = wr[u];
  } else if (u < 256) {
    val = wr[u];
  } else if (u == 256) {
    if (ul) { for (int cc = 0; cc < 128; cc++) val += wr[cc] * blin[cc]; }
  }
  OW[idx] = val;
}

__global__ __launch_bounds__(256) void k_build_F(
    float* __restrict__ Fa, const float* __restrict__ fcw, const float* __restrict__ OWa)
{
  int ci = blockIdx.y >> 1, h = blockIdx.y & 1;
  int lyr = (ci == 2) ? 1 : 0;
  int idx = blockIdx.x * 256 + threadIdx.x;   // < 256*260
  int p = idx / 260, u = idx % 260;
  const float* fw = fcw + (size_t)lyr * 65536 + (size_t)p * 256 + h * 128;
  const float* ow = OWa + (size_t)ci * 2 * 128 * 260 + (size_t)h * 128 * 260;
  float s = 0.f;
  for (int d = 0; d < 128; d++) s += fw[d] * ow[(size_t)d * 260 + u];
  Fa[(size_t)ci * 256 * 520 + (size_t)p * 520 + h * 260 + u] = s;
}

// ---------------- f16 MFMA GEMM: C[M,N] = Acat[M,K] @ B[N,K].T (+bias)(+relu)
// Acat col k: k<splitK -> A[r*lda+k] else A2[r*lda2+k-splitK]. M % BM == 0.
// cmode: 0 -> f32 store, 1 -> f16 store (C cast to _Float16*)

template<int BM, int BN>
__global__ __launch_bounds__(256) void k_mgemm(
    const float* __restrict__ A, const float* __restrict__ A2, int splitK,
    int lda, int lda2,
    const float* __restrict__ B, int ldb,
    const float* __restrict__ bias,
    float* __restrict__ C, int ldc,
    int M, int N, int K, int relu, int cmode)
{
  constexpr int BK = 64;
  constexpr int LDS = BK + 8;
  __shared__ _Float16 As[BM][LDS];
  __shared__ _Float16 Bs[BN][LDS];
  constexpr int FM = BM / 32;
  constexpr int FN = BN / 32;
  int tid = threadIdx.x;
  int wv = tid >> 6, lane = tid & 63;
  int wm = wv >> 1, wn = wv & 1;
  int row0 = blockIdx.x * BM, col0 = blockIdx.y * BN;
  int m0 = wm * (BM / 2), n0 = wn * (BN / 2);
  int lr = lane & 15, lk = lane >> 4;

  f4 acc[FM][FN];
#pragma unroll
  for (int i = 0; i < FM; i++)
#pragma unroll
    for (int j = 0; j < FN; j++) acc[i][j] = (f4)0.f;

  constexpr int TPRA = 256 / BM;
  constexpr int F4A = (BK / TPRA) / 4;
  int arow = tid / TPRA;
  int acol = (tid % TPRA) * (BK / TPRA);
  constexpr int TPRB = 256 / BN;
  constexpr int F4B = (BK / TPRB) / 4;
  int brow = tid / TPRB;
  int bcol = (tid % TPRB) * (BK / TPRB);
  int gar = row0 + arow;
  int gbr = col0 + brow;
  bool bvalid = gbr < N;

  for (int k0 = 0; k0 < K; k0 += BK) {
    __syncthreads();
#pragma unroll
    for (int j = 0; j < F4A; j++) {
      int ka = k0 + acol + j * 4;
      f4 v = (f4)0.f;
      if (ka < K) {
        const float* src = (ka < splitK) ? &A[(size_t)gar * lda + ka]
                                         : &A2[(size_t)gar * lda2 + (ka - splitK)];
        v = *(const f4*)src;
      }
      h4 hv = { (_Float16)v.x, (_Float16)v.y, (_Float16)v.z, (_Float16)v.w };
      *(h4*)&As[arow][acol + j * 4] = hv;
    }
#pragma unroll
    for (int j = 0; j < F4B; j++) {
      int ka = k0 + bcol + j * 4;
      f4 v = (f4)0.f;
      if (bvalid && ka < K) v = *(const f4*)&B[(size_t)gbr * ldb + ka];
      h4 hv = { (_Float16)v.x, (_Float16)v.y, (_Float16)v.z, (_Float16)v.w };
      *(h4*)&Bs[brow][bcol + j * 4] = hv;
    }
    __syncthreads();
#pragma unroll
    for (int kk = 0; kk < 2; kk++) {
      h8 af[FM], bf[FN];
#pragma unroll
      for (int i = 0; i < FM; i++)
        af[i] = *(h8*)&As[m0 + i * 16 + lr][kk * 32 + lk * 8];
#pragma unroll
      for (int j = 0; j < FN; j++)
        bf[j] = *(h8*)&Bs[n0 + j * 16 + lr][kk * 32 + lk * 8];
#pragma unroll
      for (int i = 0; i < FM; i++)
#pragma unroll
        for (int j = 0; j < FN; j++)
          acc[i][j] = __builtin_amdgcn_mfma_f32_16x16x32_f16(af[i], bf[j], acc[i][j], 0, 0, 0);
    }
  }
#pragma unroll
  for (int j = 0; j < FN; j++) {
    int c = col0 + n0 + j * 16 + lr;
    if (c >= N) continue;
    float bz = bias ? bias[c] : 0.f;
#pragma unroll
    for (int i = 0; i < FM; i++) {
      int rbase = row0 + m0 + i * 16 + lk * 4;
#pragma unroll
      for (int r = 0; r < 4; r++) {
        int rr = rbase + r;
        if (rr >= M) continue;
        float v = acc[i][j][r] + bz;
        if (relu && v < 0.f) v = 0.f;
        if (cmode) ((_Float16*)C)[(size_t)rr * ldc + c] = (_Float16)v;
        else C[(size_t)rr * ldc + c] = v;
      }
    }
  }
}

// ---------------- per-row score/softmax/aggregate (in place on UY) ----------

__global__ __launch_bounds__(256) void k_score(
    float* __restrict__ UY,
    const float* __restrict__ feat,   // [rows][20][128]
    const float* __restrict__ tsrc,   // [rows]
    const float* __restrict__ tngh,   // [rows][20]
    const int*   __restrict__ idx,    // [rows][20]
    const float* __restrict__ freq, const float* __restrict__ phase,
    int rows)
{
  __shared__ __align__(16) float Ush[520];
  __shared__ __align__(16) float fsh[20][132];
  __shared__ __align__(16) float tesh[20][132];
  __shared__ __align__(16) float fq[128];
  __shared__ __align__(16) float ph[128];
  __shared__ float ssh[2][20];
  __shared__ float ash[2][20];
  __shared__ float dtsh[20];
  __shared__ int msh[20];
  int row = blockIdx.x;
  if (row >= rows) return;
  int tid = threadIdx.x;
  for (int u = tid; u < 520; u += 256) Ush[u] = UY[(size_t)row * 520 + u];
  if (tid < 128) { fq[tid] = freq[tid]; ph[tid] = phase[tid]; }
  const float4* fg = (const float4*)(feat + (size_t)row * 20 * 128);
  for (int i = tid; i < 640; i += 256) {
    int j = i >> 5, c4 = i & 31;
    *(float4*)&fsh[j][c4 * 4] = fg[i];
  }
  if (tid < 20) {
    dtsh[tid] = tsrc[row] - tngh[(size_t)row * 20 + tid];
    msh[tid] = (idx[(size_t)row * 20 + tid] == 0);
  }
  __syncthreads();
  for (int i = tid; i < 2560; i += 256) {
    int j = i >> 7, t = i & 127;
    tesh[j][t] = __cosf(dtsh[j] * fq[t] + ph[t]);
  }
  __syncthreads();
  // scores: 16-lane groups, p = head*20 + j
  int wv = tid >> 6, lane = tid & 63;
  int grp = lane >> 4, li = lane & 15;
#pragma unroll
  for (int it = 0; it < 3; it++) {
    int p = it * 16 + wv * 4 + grp;
    float part = 0.f;
    int h = (p < 40) ? (p / 20) : 0;
    int j = (p < 40) ? (p - h * 20) : 0;
    if (p < 40) {
      const float* urow = Ush + h * 260;
#pragma unroll
      for (int k = 0; k < 4; k++) {
        int e = li * 4 + k * 64;
        float4 u4 = *(const float4*)&urow[e];
        float4 x4 = (e < 128) ? *(const float4*)&fsh[j][e]
                              : *(const float4*)&tesh[j][e - 128];
        part += u4.x * x4.x + u4.y * x4.y + u4.z * x4.z + u4.w * x4.w;
      }
    }
    for (int m = 8; m; m >>= 1) part += __shfl_xor(part, m, 16);
    if (p < 40 && li == 0) ssh[h][j] = part + Ush[h * 260 + 256];
  }
  __syncthreads();
  // wave-parallel softmax: wave 0 -> head 0, wave 1 -> head 1
  if (wv < 2 && lane < 32) {
    const float scale = 0.08838834764831845f; // 1/sqrt(128)
    float s = (lane < 20) ? (msh[lane] ? -1e10f : ssh[wv][lane] * scale) : -3.0e38f;
    float mx = s;
    for (int m = 16; m; m >>= 1) mx = fmaxf(mx, __shfl_xor(mx, m, 32));
    float e = (lane < 20) ? __expf(s - mx) : 0.f;
    float sum = e;
    for (int m = 16; m; m >>= 1) sum += __shfl_xor(sum, m, 32);
    if (lane < 20) ash[wv][lane] = e / sum;
  }
  __syncthreads();
  // aggregate
  float* Yrow = UY + (size_t)row * 520;
  {
    float a0 = 0.f, a1 = 0.f;
    if (tid < 128) {
#pragma unroll 5
      for (int j = 0; j < 20; j++) {
        float x = fsh[j][tid];
        a0 += ash[0][j] * x; a1 += ash[1][j] * x;
      }
    } else if (tid < 256) {
      int t2 = tid - 128;
#pragma unroll 5
      for (int j = 0; j < 20; j++) {
        float x = tesh[j][t2];
        a0 += ash[0][j] * x; a1 += ash[1][j] * x;
      }
    }
    Yrow[tid] = a0;
    Yrow[260 + tid] = a1;
  }
  if (tid < 4) {
    Yrow[256 + tid] = (tid == 0) ? 1.f : 0.f;
    Yrow[516 + tid] = (tid == 0) ? 1.f : 0.f;
  }
}

// ---------------- residual + LayerNorm ----------------

__global__ __launch_bounds__(256) void k_ln(
    float* __restrict__ P, const float* __restrict__ fcb,
    const float* __restrict__ srcv, const float* __restrict__ te0,
    const float* __restrict__ g, const float* __restrict__ b, int rows)
{
  int wave = threadIdx.x >> 6, lane = threadIdx.x & 63;
  int row = blockIdx.x * 4 + wave;
  if (row >= rows) return;
  float4 v = *(float4*)&P[(size_t)row * 256 + (lane << 2)];
  float4 fb = *(const float4*)&fcb[lane << 2];
  float4 q;
  if (lane < 32) q = *(const float4*)&srcv[(size_t)row * 128 + (lane << 2)];
  else q = *(const float4*)&te0[(lane - 32) << 2];
  v.x += fb.x + q.x; v.y += fb.y + q.y; v.z += fb.z + q.z; v.w += fb.w + q.w;
  float s = v.x + v.y + v.z + v.w;
  for (int m = 32; m; m >>= 1) s += __shfl_xor(s, m, 64);
  float mean = s * (1.0f / 256.0f);
  float d0 = v.x - mean, d1 = v.y - mean, d2 = v.z - mean, d3 = v.w - mean;
  float vs = d0 * d0 + d1 * d1 + d2 * d2 + d3 * d3;
  for (int m = 32; m; m >>= 1) vs += __shfl_xor(vs, m, 64);
  float rstd = rsqrtf(vs * (1.0f / 256.0f) + 1e-5f);
  float4 gg = *(const float4*)&g[lane << 2];
  float4 bb = *(const float4*)&b[lane << 2];
  float4 o;
  o.x = d0 * rstd * gg.x + bb.x; o.y = d1 * rstd * gg.y + bb.y;
  o.z = d2 * rstd * gg.z + bb.z; o.w = d3 * rstd * gg.w + bb.w;
  *(float4*)&P[(size_t)row * 256 + (lane << 2)] = o;
}

__global__ __launch_bounds__(256) void k_transpose(
    const float* __restrict__ src, float* __restrict__ dst, int R, int C)
{
  int idx = blockIdx.x * 256 + threadIdx.x;
  if (idx >= R * C) return;
  int c = idx / R, r = idx % R;
  dst[idx] = src[(size_t)r * C + c];
}

// ---------------- fused MFMA autoencoder loss --------------------------------
// loss partial: sum over 128x128 tile of (adj - sigmoid(z_i . z_j))^2
// z: [4096][128] f16 (1 MB, L2-resident) -> fragments loaded straight from
// global, no LDS, no barriers. 4 waves, each a 64x64 quadrant.

__global__ __launch_bounds__(256) void k_loss_mfma(
    const _Float16* __restrict__ z, const float* __restrict__ adj,
    float* __restrict__ acc)
{
  int tid = threadIdx.x;
  int wv = tid >> 6, lane = tid & 63;
  int wm = wv >> 1, wn = wv & 1;
  int lr = lane & 15, lk = lane >> 4;
  int row0 = blockIdx.x * 128 + wm * 64;
  int col0 = blockIdx.y * 128 + wn * 64;

  f4 accf[4][4];
#pragma unroll
  for (int i = 0; i < 4; i++)
#pragma unroll
    for (int j = 0; j < 4; j++) accf[i][j] = (f4)0.f;

#pragma unroll
  for (int kk = 0; kk < 4; kk++) {
    int ko = kk * 32 + lk * 8;
    h8 af[4], bf[4];
#pragma unroll
    for (int i = 0; i < 4; i++)
      af[i] = *(const h8*)&z[(size_t)(row0 + i * 16 + lr) * 128 + ko];
#pragma unroll
    for (int j = 0; j < 4; j++)
      bf[j] = *(const h8*)&z[(size_t)(col0 + j * 16 + lr) * 128 + ko];
#pragma unroll
    for (int i = 0; i < 4; i++)
#pragma unroll
      for (int j = 0; j < 4; j++)
        accf[i][j] = __builtin_amdgcn_mfma_f32_16x16x32_f16(af[i], bf[j], accf[i][j], 0, 0, 0);
  }

  float lsum = 0.f;
#pragma unroll
  for (int i = 0; i < 4; i++) {
    int rbase = row0 + i * 16 + lk * 4;
#pragma unroll
    for (int r = 0; r < 4; r++) {
      const float* arow = adj + (size_t)(rbase + r) * 4096;
#pragma unroll
      for (int j = 0; j < 4; j++) {
        float x = accf[i][j][r];
        float s = 1.0f / (1.0f + __expf(-x));
        float d = arow[col0 + j * 16 + lr] - s;
        lsum += d * d;
      }
    }
  }
  for (int m = 32; m; m >>= 1) lsum += __shfl_xor(lsum, m, 64);
  if (lane == 0) atomicAdd(acc, lsum);
}

__global__ void k_zero(float* p) { p[0] = 0.f; }
__global__ void k_final(const float* acc, float* out) {
  out[0] = acc[0] * (1.0f / (4096.0f * 4096.0f));
}

// ---------------------------------------------------------------------------

extern "C" void kernel_launch(void* const* d_in, const int* in_sizes, int n_in,
                              void* d_out, int out_size, void* d_ws, size_t ws_size,
                              hipStream_t stream) {
  const float* src_feat  = (const float*)d_in[0];
  const float* src_t     = (const float*)d_in[1];
  const int*   ngh1_idx  = (const int*)d_in[2];
  const float* ngh1_t    = (const float*)d_in[3];
  const float* ngh1_feat = (const float*)d_in[4];
  const int*   ngh2_idx  = (const int*)d_in[5];
  const float* ngh2_t    = (const float*)d_in[6];
  const float* ngh2_feat = (const float*)d_in[7];
  const float* ae_x      = (const float*)d_in[8];
  const float* ae_adj    = (const float*)d_in[9];
  const float* W_lin     = (const float*)d_in[10];
  const float* b_lin     = (const float*)d_in[11];
  const float* freq      = (const float*)d_in[12];
  const float* phase     = (const float*)d_in[13];
  const float* wq        = (const float*)d_in[14];
  const float* wk        = (const float*)d_in[15];
  const float* wv        = (const float*)d_in[16];
  const float* fcw       = (const float*)d_in[17];
  const float* fcb       = (const float*)d_in[18];
  const float* lng       = (const float*)d_in[19];
  const float* lnb       = (const float*)d_in[20];
  const float* m1w       = (const float*)d_in[21];
  const float* m1b       = (const float*)d_in[22];
  const float* m2w       = (const float*)d_in[23];
  const float* m2b       = (const float*)d_in[24];
  const float* W_gc      = (const float*)d_in[25];
  const float* b_gc      = (const float*)d_in[26];
  float* out = (float*)d_out;

  const int NB = 2048, NA = 40960;

  char* w = (char*)d_ws;
  size_t off = 0;
  auto alloc = [&](size_t bytes) -> float* {
    float* p = (float*)(w + off);
    off += (bytes + 255) & ~(size_t)255;
    return p;
  };
  float* te0    = alloc(128 * 4);
  float* linS   = alloc((size_t)NB * 128 * 4);
  float* lin1   = alloc((size_t)NA * 128 * 4);
  float* src_l1 = alloc((size_t)NB * 128 * 4);
  float* ngh_l1 = alloc((size_t)NA * 128 * 4);
  float* bq     = alloc(2 * 256 * 4);
  float* Mb     = alloc((size_t)2 * 2 * 256 * 128 * 4);
  float* cbf    = alloc(2 * 2 * 256 * 4);
  float* SW     = alloc((size_t)3 * 520 * 128 * 4);
  float* cbU    = alloc(3 * 520 * 4);
  float* OW     = alloc((size_t)3 * 2 * 128 * 260 * 4);
  float* F      = alloc((size_t)3 * 256 * 520 * 4);
  float* WgcT   = alloc(128 * 128 * 4);
  float* xw     = alloc((size_t)4096 * 128 * 4);
  float* xwT    = alloc((size_t)4096 * 128 * 4);
  _Float16* zh  = (_Float16*)alloc((size_t)4096 * 128 * 2);
  float* lacc   = alloc(256);
  size_t fixed = off;

  size_t avail = (ws_size > fixed) ? (ws_size - fixed) : 0;
  long rows_c = (long)(avail / 3720);
  if (rows_c > NA) rows_c = NA;
  rows_c &= ~127L;
  if (rows_c < 2048) rows_c = 2048;
  float* Ubuf  = alloc((size_t)rows_c * 520 * 4);
  float* Pbuf  = alloc((size_t)rows_c * 256 * 4);
  float* H1buf = alloc((size_t)rows_c * 128 * 4);

  auto gemm128 = [&](const float* A, const float* A2, int splitK, int lda, int lda2,
                     const float* Bm, int ldb, const float* bias, float* Cm, int ldc,
                     int M, int N, int Kd, int relu, int cmode) {
    dim3 g(M / 128, (N + 127) / 128);
    k_mgemm<128, 128><<<g, 256, 0, stream>>>(A, A2, splitK, lda, lda2, Bm, ldb, bias,
                                             Cm, ldc, M, N, Kd, relu, cmode);
  };
  const int BIG = 1 << 30;

  // ---- folded weights (6 launches) ----
  k_prep1<<<2, 256, 0, stream>>>(phase, wq, te0, bq);
  k_prep2<<<4, 256, 0, stream>>>(wk, bq, cbf);
  k_prepM<<<dim3(128, 4), 256, 0, stream>>>(wq, wk, Mb);
  k_build_SW<<<dim3(260, 3), 256, 0, stream>>>(SW, cbU, Mb, cbf, W_lin, b_lin);
  k_build_OW<<<dim3(260, 3), 256, 0, stream>>>(OW, wv, W_lin, b_lin);
  k_build_F<<<dim3(260, 6), 256, 0, stream>>>(F, fcw, OW);

  // ---- feature linear layers ----
  gemm128(src_feat, src_feat, BIG, 128, 128, W_lin, 128, b_lin, linS, 128, NB, 128, 128, 0, 0);
  gemm128(ngh1_feat, ngh1_feat, BIG, 128, 128, W_lin, 128, b_lin, lin1, 128, NA, 128, 128, 0, 0);

  // ---- attention calls ----
  auto attn_call = [&](int ci, long rows_total, const float* srcvec,
                       const float* featp, const float* tsrcp, const float* tnghp,
                       const int* idxp, int l, float* outp) {
    for (long r0 = 0; r0 < rows_total; r0 += rows_c) {
      long rem = rows_total - r0;
      int rows = (int)(rem < rows_c ? rem : rows_c);
      gemm128(srcvec + r0 * 128, srcvec, BIG, 128, 128,
              SW + (size_t)ci * 520 * 128, 128, cbU + ci * 520, Ubuf, 520, rows, 520, 128, 0, 0);
      k_score<<<rows, 256, 0, stream>>>(Ubuf, featp + r0 * 20 * 128, tsrcp + r0,
                                        tnghp + r0 * 20, idxp + r0 * 20, freq, phase, rows);
      gemm128(Ubuf, Ubuf, BIG, 520, 520, F + (size_t)ci * 256 * 520, 520, nullptr,
              Pbuf, 256, rows, 256, 520, 0, 0);
      k_ln<<<(rows + 3) / 4, 256, 0, stream>>>(Pbuf, fcb + l * 256, srcvec + r0 * 128,
                                               te0, lng + l * 256, lnb + l * 256, rows);
      gemm128(Pbuf, srcvec + r0 * 128, 256, 256, 128, m1w + (size_t)l * 128 * 384, 384,
              m1b + l * 128, H1buf, 128, rows, 128, 384, 1, 0);
      gemm128(H1buf, H1buf, BIG, 128, 128, m2w + (size_t)l * 128 * 128, 128,
              m2b + l * 128, outp + r0 * 128, 128, rows, 128, 128, 0, 0);
    }
  };
  attn_call(0, NA, lin1, ngh2_feat, ngh1_t, ngh2_t, ngh2_idx, 0, ngh_l1);
  attn_call(1, NB, linS, lin1, src_t, ngh1_t, ngh1_idx, 0, src_l1);
  attn_call(2, NB, src_l1, ngh_l1, src_t, ngh1_t, ngh1_idx, 1, out);

  // ---- autoencoder loss ----
  k_transpose<<<(128 * 128 + 255) / 256, 256, 0, stream>>>(W_gc, WgcT, 128, 128);
  gemm128(ae_x, ae_x, BIG, 128, 128, WgcT, 128, nullptr, xw, 128, 4096, 128, 128, 0, 0);
  k_transpose<<<(4096 * 128 + 255) / 256, 256, 0, stream>>>(xw, xwT, 4096, 128);
  {
    dim3 g(4096 / 64, 128 / 64);
    k_mgemm<64, 64><<<g, 256, 0, stream>>>(ae_adj, ae_adj, BIG, 4096, 4096, xwT, 4096,
                                           b_gc, (float*)zh, 128, 4096, 128, 4096, 0, 1);
  }
  k_zero<<<1, 1, 0, stream>>>(lacc);
  k_loss_mfma<<<dim3(32, 32), 256, 0, stream>>>(zh, ae_adj, lacc);
  k_final<<<1, 1, 0, stream>>>(lacc, out + (size_t)NB * 128);
}

// Round 4
// 746.249 us; speedup vs baseline: 2.7045x; 1.4535x over previous
//
#include <hip/hip_runtime.h>
#include <math.h>

// ---------------------------------------------------------------------------
// TGAT classifier. Algebraic folding (score/aggregate in input space,
// wq/wk/wv/W_lin/fc_w folded into SW/F), f16 MFMA everywhere, f16
// intermediates, fused P-GEMM+LayerNorm, fused MergeLayer (m1+relu+m2),
// fused MFMA autoencoder loss.
// ---------------------------------------------------------------------------

typedef _Float16 h4 __attribute__((ext_vector_type(4)));
typedef _Float16 h8 __attribute__((ext_vector_type(8)));
typedef float f4 __attribute__((ext_vector_type(4)));

// ---------------- setup fold kernels ----------------

__global__ __launch_bounds__(256) void k_prep1(
    const float* __restrict__ phase, const float* __restrict__ wq,
    float* __restrict__ te0, float* __restrict__ bq)
{
  int l = blockIdx.x, t = threadIdx.x;
  __shared__ float te[128];
  if (t < 128) te[t] = cosf(phase[t]);
  __syncthreads();
  if (l == 0 && t < 128) te0[t] = te[t];
  const float* wr = wq + ((size_t)l * 256 + t) * 256 + 128;
  float s = 0.f;
  for (int k = 0; k < 128; k++) s += wr[k] * te[k];
  bq[l * 256 + t] = s;
}

__global__ __launch_bounds__(256) void k_prep2(
    const float* __restrict__ wk, const float* __restrict__ bq, float* __restrict__ cbf)
{
  int lh = blockIdx.x, l = lh >> 1, h = lh & 1, e = threadIdx.x;
  const float* wkb = wk + (size_t)l * 65536 + (size_t)h * 128 * 256;
  const float* bqb = bq + l * 256 + h * 128;
  float s = 0.f;
  for (int d = 0; d < 128; d++) s += wkb[(size_t)d * 256 + e] * bqb[d];
  cbf[lh * 256 + e] = s;
}

__global__ __launch_bounds__(256) void k_prepM(
    const float* __restrict__ wq, const float* __restrict__ wk, float* __restrict__ Mb)
{
  int lh = blockIdx.y, l = lh >> 1, h = lh & 1;
  int idx = blockIdx.x * 256 + threadIdx.x;   // < 256*128
  int e = idx >> 7, s = idx & 127;
  const float* wkb = wk + (size_t)l * 65536 + (size_t)h * 128 * 256;
  const float* wqb = wq + (size_t)l * 65536 + (size_t)h * 128 * 256;
  float acc = 0.f;
  for (int d = 0; d < 128; d++) acc += wkb[(size_t)d * 256 + e] * wqb[(size_t)d * 256 + s];
  Mb[(size_t)lh * 32768 + idx] = acc;
}

// SW emitted f16 (B-operand of U-GEMM), cb f32
__global__ __launch_bounds__(256) void k_build_SW(
    _Float16* __restrict__ SWa, float* __restrict__ cba,
    const float* __restrict__ Mb, const float* __restrict__ cbf,
    const float* __restrict__ Wlin, const float* __restrict__ blin)
{
  int ci = blockIdx.y;
  int lyr = (ci == 2) ? 1 : 0;
  int ul  = (ci == 0) ? 1 : 0;
  const float* M2 = Mb + (size_t)lyr * 2 * 32768;
  const float* c2 = cbf + (size_t)lyr * 512;
  _Float16* SW = SWa + (size_t)ci * 520 * 128;
  float* cb = cba + (size_t)ci * 520;
  int idx = blockIdx.x * 256 + threadIdx.x;
  if (idx >= 520 * 128) return;
  int urow = idx / 128, s = idx % 128;
  int h = urow / 260, u = urow % 260;
  const float* M = M2 + (size_t)h * 32768;
  const float* c = c2 + h * 256;
  float val = 0.f, cbv = 0.f;
  if (u < 128) {
    if (ul) {
      for (int cc = 0; cc < 128; cc++) {
        float w = Wlin[cc * 128 + u];
        val += w * M[cc * 128 + s];
        cbv += w * c[cc];
      }
    } else { val = M[u * 128 + s]; cbv = c[u]; }
  } else if (u < 256) {
    val = M[u * 128 + s]; cbv = c[u];
  } else if (u == 256) {
    if (ul) {
      for (int cc = 0; cc < 128; cc++) {
        float w = blin[cc];
        val += w * M[cc * 128 + s];
        cbv += w * c[cc];
      }
    }
  }
  SW[(size_t)urow * 128 + s] = (_Float16)val;
  if (s == 0) cb[urow] = cbv;
}

__global__ __launch_bounds__(256) void k_build_OW(
    float* __restrict__ OWa, const float* __restrict__ wv,
    const float* __restrict__ Wlin, const float* __restrict__ blin)
{
  int ci = blockIdx.y;
  int lyr = (ci == 2) ? 1 : 0;
  int ul  = (ci == 0) ? 1 : 0;
  float* OW = OWa + (size_t)ci * 2 * 128 * 260;
  const float* wvl = wv + (size_t)lyr * 65536;
  int idx = blockIdx.x * 256 + threadIdx.x;
  if (idx >= 2 * 128 * 260) return;
  int u = idx % 260; int d = (idx / 260) % 128; int h = idx / (260 * 128);
  const float* wr = wvl + (size_t)(h * 128 + d) * 256;
  float val = 0.f;
  if (u < 128) {
    if (ul) { for (int cc = 0; cc < 128; cc++) val += wr[cc] * Wlin[cc * 128 + u]; }
    else val = wr[u];
  } else if (u < 256) {
    val = wr[u];
  } else if (u == 256) {
    if (ul) { for (int cc = 0; cc < 128; cc++) val += wr[cc] * blin[cc]; }
  }
  OW[idx] = val;
}

// F emitted f16 (B-operand of P-GEMM)
__global__ __launch_bounds__(256) void k_build_F(
    _Float16* __restrict__ Fa, const float* __restrict__ fcw, const float* __restrict__ OWa)
{
  int ci = blockIdx.y >> 1, h = blockIdx.y & 1;
  int lyr = (ci == 2) ? 1 : 0;
  int idx = blockIdx.x * 256 + threadIdx.x;   // < 256*260
  int p = idx / 260, u = idx % 260;
  const float* fw = fcw + (size_t)lyr * 65536 + (size_t)p * 256 + h * 128;
  const float* ow = OWa + (size_t)ci * 2 * 128 * 260 + (size_t)h * 128 * 260;
  float s = 0.f;
  for (int d = 0; d < 128; d++) s += fw[d] * ow[(size_t)d * 260 + u];
  Fa[(size_t)ci * 256 * 520 + (size_t)p * 520 + h * 260 + u] = (_Float16)s;
}

__global__ __launch_bounds__(256) void k_f2h(
    const float* __restrict__ s, _Float16* __restrict__ d, int n)
{
  int i = blockIdx.x * 256 + threadIdx.x;
  if (i < n) d[i] = (_Float16)s[i];
}

// dst[C][R] f16 = src[R][C] f32
__global__ __launch_bounds__(256) void k_transpose_f2h(
    const float* __restrict__ src, _Float16* __restrict__ dst, int R, int C)
{
  int idx = blockIdx.x * 256 + threadIdx.x;
  if (idx >= R * C) return;
  int c = idx / R, r = idx % R;
  dst[idx] = (_Float16)src[(size_t)r * C + c];
}

__global__ __launch_bounds__(256) void k_transpose_h(
    const _Float16* __restrict__ src, _Float16* __restrict__ dst, int R, int C)
{
  int idx = blockIdx.x * 256 + threadIdx.x;
  if (idx >= R * C) return;
  int c = idx / R, r = idx % R;
  dst[idx] = src[(size_t)r * C + c];
}

// ---------------- generic f16 MFMA GEMM: C[M,N] = A[M,K](f32) @ Bh[N,K].T
// (+bias f32)  cmode: 0 -> f32 store, 1 -> f16 store.  M % BM == 0.

template<int BM, int BN>
__global__ __launch_bounds__(256) void k_mgemm(
    const float* __restrict__ A, int lda,
    const _Float16* __restrict__ Bh, int ldb,
    const float* __restrict__ bias,
    float* __restrict__ C, int ldc,
    int M, int N, int K, int cmode)
{
  constexpr int BK = 64;
  constexpr int LDS = BK + 8;
  __shared__ _Float16 As[BM][LDS];
  __shared__ _Float16 Bs[BN][LDS];
  constexpr int FM = BM / 32;
  constexpr int FN = BN / 32;
  int tid = threadIdx.x;
  int wv = tid >> 6, lane = tid & 63;
  int wm = wv >> 1, wn = wv & 1;
  int row0 = blockIdx.x * BM, col0 = blockIdx.y * BN;
  int m0 = wm * (BM / 2), n0 = wn * (BN / 2);
  int lr = lane & 15, lk = lane >> 4;

  f4 acc[FM][FN];
#pragma unroll
  for (int i = 0; i < FM; i++)
#pragma unroll
    for (int j = 0; j < FN; j++) acc[i][j] = (f4)0.f;

  constexpr int TPRA = 256 / BM;
  constexpr int F4A = (BK / TPRA) / 4;
  int arow = tid / TPRA;
  int acol = (tid % TPRA) * (BK / TPRA);
  constexpr int TPRB = 256 / BN;
  constexpr int F4B = (BK / TPRB) / 4;
  int brow = tid / TPRB;
  int bcol = (tid % TPRB) * (BK / TPRB);
  int gar = row0 + arow;
  int gbr = col0 + brow;
  bool bvalid = gbr < N;

  for (int k0 = 0; k0 < K; k0 += BK) {
    __syncthreads();
#pragma unroll
    for (int j = 0; j < F4A; j++) {
      int ka = k0 + acol + j * 4;
      f4 v = (f4)0.f;
      if (ka < K) v = *(const f4*)&A[(size_t)gar * lda + ka];
      h4 hv = { (_Float16)v.x, (_Float16)v.y, (_Float16)v.z, (_Float16)v.w };
      *(h4*)&As[arow][acol + j * 4] = hv;
    }
#pragma unroll
    for (int j = 0; j < F4B; j++) {
      int ka = k0 + bcol + j * 4;
      h4 hv = (h4)(_Float16)0.f;
      if (bvalid && ka < K) hv = *(const h4*)&Bh[(size_t)gbr * ldb + ka];
      *(h4*)&Bs[brow][bcol + j * 4] = hv;
    }
    __syncthreads();
#pragma unroll
    for (int kk = 0; kk < 2; kk++) {
      h8 af[FM], bf[FN];
#pragma unroll
      for (int i = 0; i < FM; i++)
        af[i] = *(h8*)&As[m0 + i * 16 + lr][kk * 32 + lk * 8];
#pragma unroll
      for (int j = 0; j < FN; j++)
        bf[j] = *(h8*)&Bs[n0 + j * 16 + lr][kk * 32 + lk * 8];
#pragma unroll
      for (int i = 0; i < FM; i++)
#pragma unroll
        for (int j = 0; j < FN; j++)
          acc[i][j] = __builtin_amdgcn_mfma_f32_16x16x32_f16(af[i], bf[j], acc[i][j], 0, 0, 0);
    }
  }
#pragma unroll
  for (int j = 0; j < FN; j++) {
    int c = col0 + n0 + j * 16 + lr;
    if (c >= N) continue;
    float bz = bias ? bias[c] : 0.f;
#pragma unroll
    for (int i = 0; i < FM; i++) {
      int rbase = row0 + m0 + i * 16 + lk * 4;
#pragma unroll
      for (int r = 0; r < 4; r++) {
        int rr = rbase + r;
        float v = acc[i][j][r] + bz;
        if (cmode) ((_Float16*)C)[(size_t)rr * ldc + c] = (_Float16)v;
        else C[(size_t)rr * ldc + c] = v;
      }
    }
  }
}

// ---------------- fused P-GEMM + residual + LayerNorm ------------------------
// P[64 rows][256] = U[rows][520](f16) @ F[256][520].T ; then
// v = P + fcb + q (q=[src f32 | te0]); LN over 256 cols; store f16.

__global__ __launch_bounds__(256) void k_pgemm_ln(
    const _Float16* __restrict__ U, const _Float16* __restrict__ F,
    const float* __restrict__ fcb, const float* __restrict__ srcv,
    const float* __restrict__ te0,
    const float* __restrict__ g, const float* __restrict__ b,
    _Float16* __restrict__ P, int rows)
{
  constexpr int BK = 64, LDSC = BK + 8;
  __shared__ _Float16 As[64][LDSC];
  __shared__ _Float16 Bs[256][LDSC];
  __shared__ float redS[64][4];
  __shared__ float redQ[64][4];
  __shared__ float mrow[64];
  __shared__ float rrow[64];
  int tid = threadIdx.x;
  int wv = tid >> 6, lane = tid & 63;
  int lr = lane & 15, lk = lane >> 4;
  int row0 = blockIdx.x * 64;
  int n0 = wv * 64;

  f4 acc[4][4];
#pragma unroll
  for (int i = 0; i < 4; i++)
#pragma unroll
    for (int j = 0; j < 4; j++) acc[i][j] = (f4)0.f;

  int arow = tid >> 2;
  int acol = (tid & 3) * 16;
  for (int k0 = 0; k0 < 520; k0 += BK) {
    __syncthreads();
#pragma unroll
    for (int j = 0; j < 4; j++) {
      int ka = k0 + acol + j * 4;
      h4 hv = (h4)(_Float16)0.f;
      if (ka < 520) hv = *(const h4*)&U[(size_t)(row0 + arow) * 520 + ka];
      *(h4*)&As[arow][acol + j * 4] = hv;
    }
#pragma unroll
    for (int j = 0; j < 16; j++) {
      int ka = k0 + j * 4;
      h4 hv = (h4)(_Float16)0.f;
      if (ka < 520) hv = *(const h4*)&F[(size_t)tid * 520 + ka];
      *(h4*)&Bs[tid][j * 4] = hv;
    }
    __syncthreads();
#pragma unroll
    for (int kk = 0; kk < 2; kk++) {
      h8 af[4], bf[4];
#pragma unroll
      for (int i = 0; i < 4; i++)
        af[i] = *(h8*)&As[i * 16 + lr][kk * 32 + lk * 8];
#pragma unroll
      for (int j = 0; j < 4; j++)
        bf[j] = *(h8*)&Bs[n0 + j * 16 + lr][kk * 32 + lk * 8];
#pragma unroll
      for (int i = 0; i < 4; i++)
#pragma unroll
        for (int j = 0; j < 4; j++)
          acc[i][j] = __builtin_amdgcn_mfma_f32_16x16x32_f16(af[i], bf[j], acc[i][j], 0, 0, 0);
    }
  }
  // epilogue: v = P + fcb + q; per-row reduce for LN
#pragma unroll
  for (int i = 0; i < 4; i++) {
#pragma unroll
    for (int r = 0; r < 4; r++) {
      int row_l = i * 16 + lk * 4 + r;
      float rs = 0.f, rq = 0.f;
#pragma unroll
      for (int j = 0; j < 4; j++) {
        int c = n0 + j * 16 + lr;
        float q = (c < 128) ? srcv[(size_t)(row0 + row_l) * 128 + c] : te0[c - 128];
        float v = acc[i][j][r] + fcb[c] + q;
        acc[i][j][r] = v;
        rs += v; rq += v * v;
      }
      for (int m = 8; m; m >>= 1) {
        rs += __shfl_xor(rs, m, 16);
        rq += __shfl_xor(rq, m, 16);
      }
      if (lr == 0) { redS[row_l][wv] = rs; redQ[row_l][wv] = rq; }
    }
  }
  __syncthreads();
  if (tid < 64) {
    float s4 = redS[tid][0] + redS[tid][1] + redS[tid][2] + redS[tid][3];
    float q4 = redQ[tid][0] + redQ[tid][1] + redQ[tid][2] + redQ[tid][3];
    float mean = s4 * (1.0f / 256.0f);
    float var = q4 * (1.0f / 256.0f) - mean * mean;
    mrow[tid] = mean;
    rrow[tid] = rsqrtf(var + 1e-5f);
  }
  __syncthreads();
#pragma unroll
  for (int i = 0; i < 4; i++) {
#pragma unroll
    for (int r = 0; r < 4; r++) {
      int row_l = i * 16 + lk * 4 + r;
      float mean = mrow[row_l], rstd = rrow[row_l];
#pragma unroll
      for (int j = 0; j < 4; j++) {
        int c = n0 + j * 16 + lr;
        float o = (acc[i][j][r] - mean) * rstd * g[c] + b[c];
        P[(size_t)(row0 + row_l) * 256 + c] = (_Float16)o;
      }
    }
  }
}

// ---------------- fused MergeLayer: out = m2(relu(m1([P|src]))) --------------
// per block: 64 rows. m1: K=384 ([P f16 256 | src f32 128]), H 64x128 -> LDS;
// m2: K=128. out f32.

__global__ __launch_bounds__(256) void k_merge(
    const _Float16* __restrict__ P, const float* __restrict__ src,
    const _Float16* __restrict__ m1w, const float* __restrict__ m1b,
    const _Float16* __restrict__ m2w, const float* __restrict__ m2b,
    float* __restrict__ out, int rows)
{
  constexpr int LDSC = 72;
  __shared__ _Float16 As[64][LDSC];
  __shared__ _Float16 Bs[128][LDSC];
  __shared__ _Float16 Hs[64][136];
  __shared__ _Float16 Ws[128][136];
  int tid = threadIdx.x;
  int wv = tid >> 6, lane = tid & 63;
  int wm = wv >> 1, wn = wv & 1;
  int lr = lane & 15, lk = lane >> 4;
  int row0 = blockIdx.x * 64;

  // stage m2w once
#pragma unroll
  for (int j = 0; j < 16; j++) {
    int ka = (tid & 1) * 64 + j * 4;
    *(h4*)&Ws[tid >> 1][ka] = *(const h4*)&m2w[(size_t)(tid >> 1) * 128 + ka];
  }

  f4 acc[2][4];
#pragma unroll
  for (int i = 0; i < 2; i++)
#pragma unroll
    for (int j = 0; j < 4; j++) acc[i][j] = (f4)0.f;

  int arow = tid >> 2;
  int acol = (tid & 3) * 16;
  int brow = tid >> 1;
  int bcol = (tid & 1) * 32;
  for (int k0 = 0; k0 < 384; k0 += 64) {
    __syncthreads();
#pragma unroll
    for (int j = 0; j < 4; j++) {
      int ka = k0 + acol + j * 4;
      h4 hv;
      if (ka < 256) {
        hv = *(const h4*)&P[(size_t)(row0 + arow) * 256 + ka];
      } else {
        f4 v = *(const f4*)&src[(size_t)(row0 + arow) * 128 + (ka - 256)];
        hv = h4{ (_Float16)v.x, (_Float16)v.y, (_Float16)v.z, (_Float16)v.w };
      }
      *(h4*)&As[arow][acol + j * 4] = hv;
    }
#pragma unroll
    for (int j = 0; j < 8; j++) {
      int ka = k0 + bcol + j * 4;
      *(h4*)&Bs[brow][bcol + j * 4] = *(const h4*)&m1w[(size_t)brow * 384 + ka];
    }
    __syncthreads();
#pragma unroll
    for (int kk = 0; kk < 2; kk++) {
      h8 af[2], bf[4];
#pragma unroll
      for (int i = 0; i < 2; i++)
        af[i] = *(h8*)&As[wm * 32 + i * 16 + lr][kk * 32 + lk * 8];
#pragma unroll
      for (int j = 0; j < 4; j++)
        bf[j] = *(h8*)&Bs[wn * 64 + j * 16 + lr][kk * 32 + lk * 8];
#pragma unroll
      for (int i = 0; i < 2; i++)
#pragma unroll
        for (int j = 0; j < 4; j++)
          acc[i][j] = __builtin_amdgcn_mfma_f32_16x16x32_f16(af[i], bf[j], acc[i][j], 0, 0, 0);
    }
  }
  // H = relu(acc + m1b) -> Hs
  __syncthreads();
#pragma unroll
  for (int i = 0; i < 2; i++) {
#pragma unroll
    for (int j = 0; j < 4; j++) {
      int c = wn * 64 + j * 16 + lr;
      float bz = m1b[c];
#pragma unroll
      for (int r = 0; r < 4; r++) {
        int row_l = wm * 32 + i * 16 + lk * 4 + r;
        float v = acc[i][j][r] + bz;
        if (v < 0.f) v = 0.f;
        Hs[row_l][c] = (_Float16)v;
      }
    }
  }
  __syncthreads();
  // m2: K=128
  f4 acc2[2][4];
#pragma unroll
  for (int i = 0; i < 2; i++)
#pragma unroll
    for (int j = 0; j < 4; j++) acc2[i][j] = (f4)0.f;
#pragma unroll
  for (int kk = 0; kk < 4; kk++) {
    h8 af[2], bf[4];
#pragma unroll
    for (int i = 0; i < 2; i++)
      af[i] = *(h8*)&Hs[wm * 32 + i * 16 + lr][kk * 32 + lk * 8];
#pragma unroll
    for (int j = 0; j < 4; j++)
      bf[j] = *(h8*)&Ws[wn * 64 + j * 16 + lr][kk * 32 + lk * 8];
#pragma unroll
    for (int i = 0; i < 2; i++)
#pragma unroll
      for (int j = 0; j < 4; j++)
        acc2[i][j] = __builtin_amdgcn_mfma_f32_16x16x32_f16(af[i], bf[j], acc2[i][j], 0, 0, 0);
  }
#pragma unroll
  for (int j = 0; j < 4; j++) {
    int c = wn * 64 + j * 16 + lr;
    float bz = m2b[c];
#pragma unroll
    for (int i = 0; i < 2; i++) {
#pragma unroll
      for (int r = 0; r < 4; r++) {
        int row_l = wm * 32 + i * 16 + lk * 4 + r;
        out[(size_t)(row0 + row_l) * 128 + c] = acc2[i][j][r] + bz;
      }
    }
  }
}

// ---------------- per-row score/softmax/aggregate (in place on U f16) -------

__global__ __launch_bounds__(256) void k_score(
    _Float16* __restrict__ UY,
    const float* __restrict__ feat,   // [rows][20][128]
    const float* __restrict__ tsrc,   // [rows]
    const float* __restrict__ tngh,   // [rows][20]
    const int*   __restrict__ idx,    // [rows][20]
    const float* __restrict__ freq, const float* __restrict__ phase,
    int rows)
{
  __shared__ __align__(16) float Ush[520];
  __shared__ __align__(16) float fsh[20][132];
  __shared__ __align__(16) float tesh[20][132];
  __shared__ __align__(16) float fq[128];
  __shared__ __align__(16) float ph[128];
  __shared__ float ssh[2][20];
  __shared__ float ash[2][20];
  __shared__ float dtsh[20];
  __shared__ int msh[20];
  int row = blockIdx.x;
  if (row >= rows) return;
  int tid = threadIdx.x;
  for (int u = tid; u < 520; u += 256) Ush[u] = (float)UY[(size_t)row * 520 + u];
  if (tid < 128) { fq[tid] = freq[tid]; ph[tid] = phase[tid]; }
  const float4* fg = (const float4*)(feat + (size_t)row * 20 * 128);
  for (int i = tid; i < 640; i += 256) {
    int j = i >> 5, c4 = i & 31;
    *(float4*)&fsh[j][c4 * 4] = fg[i];
  }
  if (tid < 20) {
    dtsh[tid] = tsrc[row] - tngh[(size_t)row * 20 + tid];
    msh[tid] = (idx[(size_t)row * 20 + tid] == 0);
  }
  __syncthreads();
  for (int i = tid; i < 2560; i += 256) {
    int j = i >> 7, t = i & 127;
    tesh[j][t] = __cosf(dtsh[j] * fq[t] + ph[t]);
  }
  __syncthreads();
  int wv = tid >> 6, lane = tid & 63;
  int grp = lane >> 4, li = lane & 15;
#pragma unroll
  for (int it = 0; it < 3; it++) {
    int p = it * 16 + wv * 4 + grp;
    float part = 0.f;
    int h = (p < 40) ? (p / 20) : 0;
    int j = (p < 40) ? (p - h * 20) : 0;
    if (p < 40) {
      const float* urow = Ush + h * 260;
#pragma unroll
      for (int k = 0; k < 4; k++) {
        int e = li * 4 + k * 64;
        float4 u4 = *(const float4*)&urow[e];
        float4 x4 = (e < 128) ? *(const float4*)&fsh[j][e]
                              : *(const float4*)&tesh[j][e - 128];
        part += u4.x * x4.x + u4.y * x4.y + u4.z * x4.z + u4.w * x4.w;
      }
    }
    for (int m = 8; m; m >>= 1) part += __shfl_xor(part, m, 16);
    if (p < 40 && li == 0) ssh[h][j] = part + Ush[h * 260 + 256];
  }
  __syncthreads();
  if (wv < 2 && lane < 32) {
    const float scale = 0.08838834764831845f; // 1/sqrt(128)
    float s = (lane < 20) ? (msh[lane] ? -1e10f : ssh[wv][lane] * scale) : -3.0e38f;
    float mx = s;
    for (int m = 16; m; m >>= 1) mx = fmaxf(mx, __shfl_xor(mx, m, 32));
    float e = (lane < 20) ? __expf(s - mx) : 0.f;
    float sum = e;
    for (int m = 16; m; m >>= 1) sum += __shfl_xor(sum, m, 32);
    if (lane < 20) ash[wv][lane] = e / sum;
  }
  __syncthreads();
  _Float16* Yrow = UY + (size_t)row * 520;
  {
    float a0 = 0.f, a1 = 0.f;
    if (tid < 128) {
#pragma unroll 5
      for (int j = 0; j < 20; j++) {
        float x = fsh[j][tid];
        a0 += ash[0][j] * x; a1 += ash[1][j] * x;
      }
    } else {
      int t2 = tid - 128;
#pragma unroll 5
      for (int j = 0; j < 20; j++) {
        float x = tesh[j][t2];
        a0 += ash[0][j] * x; a1 += ash[1][j] * x;
      }
    }
    Yrow[tid] = (_Float16)a0;
    Yrow[260 + tid] = (_Float16)a1;
  }
  if (tid < 4) {
    Yrow[256 + tid] = (_Float16)((tid == 0) ? 1.f : 0.f);
    Yrow[516 + tid] = (_Float16)((tid == 0) ? 1.f : 0.f);
  }
}

// ---------------- fused MFMA autoencoder loss --------------------------------

__global__ __launch_bounds__(256) void k_loss_mfma(
    const _Float16* __restrict__ z, const float* __restrict__ adj,
    float* __restrict__ acc)
{
  int tid = threadIdx.x;
  int wv = tid >> 6, lane = tid & 63;
  int wm = wv >> 1, wn = wv & 1;
  int lr = lane & 15, lk = lane >> 4;
  int row0 = blockIdx.x * 128 + wm * 64;
  int col0 = blockIdx.y * 128 + wn * 64;

  f4 accf[4][4];
#pragma unroll
  for (int i = 0; i < 4; i++)
#pragma unroll
    for (int j = 0; j < 4; j++) accf[i][j] = (f4)0.f;

#pragma unroll
  for (int kk = 0; kk < 4; kk++) {
    int ko = kk * 32 + lk * 8;
    h8 af[4], bf[4];
#pragma unroll
    for (int i = 0; i < 4; i++)
      af[i] = *(const h8*)&z[(size_t)(row0 + i * 16 + lr) * 128 + ko];
#pragma unroll
    for (int j = 0; j < 4; j++)
      bf[j] = *(const h8*)&z[(size_t)(col0 + j * 16 + lr) * 128 + ko];
#pragma unroll
    for (int i = 0; i < 4; i++)
#pragma unroll
      for (int j = 0; j < 4; j++)
        accf[i][j] = __builtin_amdgcn_mfma_f32_16x16x32_f16(af[i], bf[j], accf[i][j], 0, 0, 0);
  }

  float lsum = 0.f;
#pragma unroll
  for (int i = 0; i < 4; i++) {
    int rbase = row0 + i * 16 + lk * 4;
#pragma unroll
    for (int r = 0; r < 4; r++) {
      const float* arow = adj + (size_t)(rbase + r) * 4096;
#pragma unroll
      for (int j = 0; j < 4; j++) {
        float x = accf[i][j][r];
        float s = 1.0f / (1.0f + __expf(-x));
        float d = arow[col0 + j * 16 + lr] - s;
        lsum += d * d;
      }
    }
  }
  for (int m = 32; m; m >>= 1) lsum += __shfl_xor(lsum, m, 64);
  if (lane == 0) atomicAdd(acc, lsum);
}

__global__ void k_zero(float* p) { p[0] = 0.f; }
__global__ void k_final(const float* acc, float* out) {
  out[0] = acc[0] * (1.0f / (4096.0f * 4096.0f));
}

// ---------------------------------------------------------------------------

extern "C" void kernel_launch(void* const* d_in, const int* in_sizes, int n_in,
                              void* d_out, int out_size, void* d_ws, size_t ws_size,
                              hipStream_t stream) {
  const float* src_feat  = (const float*)d_in[0];
  const float* src_t     = (const float*)d_in[1];
  const int*   ngh1_idx  = (const int*)d_in[2];
  const float* ngh1_t    = (const float*)d_in[3];
  const float* ngh1_feat = (const float*)d_in[4];
  const int*   ngh2_idx  = (const int*)d_in[5];
  const float* ngh2_t    = (const float*)d_in[6];
  const float* ngh2_feat = (const float*)d_in[7];
  const float* ae_x      = (const float*)d_in[8];
  const float* ae_adj    = (const float*)d_in[9];
  const float* W_lin     = (const float*)d_in[10];
  const float* b_lin     = (const float*)d_in[11];
  const float* freq      = (const float*)d_in[12];
  const float* phase     = (const float*)d_in[13];
  const float* wq        = (const float*)d_in[14];
  const float* wk        = (const float*)d_in[15];
  const float* wv        = (const float*)d_in[16];
  const float* fcw       = (const float*)d_in[17];
  const float* fcb       = (const float*)d_in[18];
  const float* lng       = (const float*)d_in[19];
  const float* lnb       = (const float*)d_in[20];
  const float* m1w       = (const float*)d_in[21];
  const float* m1b       = (const float*)d_in[22];
  const float* m2w       = (const float*)d_in[23];
  const float* m2b       = (const float*)d_in[24];
  const float* W_gc      = (const float*)d_in[25];
  const float* b_gc      = (const float*)d_in[26];
  float* out = (float*)d_out;

  const int NB = 2048, NA = 40960;

  char* w = (char*)d_ws;
  size_t off = 0;
  auto alloc = [&](size_t bytes) -> void* {
    void* p = (void*)(w + off);
    off += (bytes + 255) & ~(size_t)255;
    return p;
  };
  float* te0    = (float*)alloc(128 * 4);
  float* linS   = (float*)alloc((size_t)NB * 128 * 4);
  float* lin1   = (float*)alloc((size_t)NA * 128 * 4);
  float* src_l1 = (float*)alloc((size_t)NB * 128 * 4);
  float* ngh_l1 = (float*)alloc((size_t)NA * 128 * 4);
  float* bq     = (float*)alloc(2 * 256 * 4);
  float* Mb     = (float*)alloc((size_t)2 * 2 * 256 * 128 * 4);
  float* cbf    = (float*)alloc(2 * 2 * 256 * 4);
  _Float16* SWh = (_Float16*)alloc((size_t)3 * 520 * 128 * 2);
  float* cbU    = (float*)alloc(3 * 520 * 4);
  float* OW     = (float*)alloc((size_t)3 * 2 * 128 * 260 * 4);
  _Float16* Fh  = (_Float16*)alloc((size_t)3 * 256 * 520 * 2);
  _Float16* Wlinh = (_Float16*)alloc(16384 * 2);
  _Float16* m1wh  = (_Float16*)alloc((size_t)2 * 128 * 384 * 2);
  _Float16* m2wh  = (_Float16*)alloc((size_t)2 * 128 * 128 * 2);
  _Float16* WgcTh = (_Float16*)alloc(16384 * 2);
  _Float16* xwh   = (_Float16*)alloc((size_t)4096 * 128 * 2);
  _Float16* xwTh  = (_Float16*)alloc((size_t)4096 * 128 * 2);
  _Float16* zh    = (_Float16*)alloc((size_t)4096 * 128 * 2);
  float* lacc   = (float*)alloc(256);
  size_t fixed = off;

  size_t avail = (ws_size > fixed) ? (ws_size - fixed) : 0;
  long rows_c = (long)(avail / 1800);   // (520+256)*2 B/row + margin
  if (rows_c > NA) rows_c = NA;
  rows_c &= ~127L;
  if (rows_c < 2048) rows_c = 2048;
  _Float16* Ubuf = (_Float16*)alloc((size_t)rows_c * 520 * 2);
  _Float16* Pbuf = (_Float16*)alloc((size_t)rows_c * 256 * 2);

  auto gemm128 = [&](const float* A, int lda, const _Float16* Bm, int ldb,
                     const float* bias, float* Cm, int ldc,
                     int M, int N, int Kd, int cmode) {
    dim3 g(M / 128, (N + 127) / 128);
    k_mgemm<128, 128><<<g, 256, 0, stream>>>(A, lda, Bm, ldb, bias, Cm, ldc, M, N, Kd, cmode);
  };

  // ---- folded weights ----
  k_prep1<<<2, 256, 0, stream>>>(phase, wq, te0, bq);
  k_prep2<<<4, 256, 0, stream>>>(wk, bq, cbf);
  k_prepM<<<dim3(128, 4), 256, 0, stream>>>(wq, wk, Mb);
  k_build_SW<<<dim3(260, 3), 256, 0, stream>>>(SWh, cbU, Mb, cbf, W_lin, b_lin);
  k_build_OW<<<dim3(260, 3), 256, 0, stream>>>(OW, wv, W_lin, b_lin);
  k_build_F<<<dim3(260, 6), 256, 0, stream>>>(Fh, fcw, OW);
  k_f2h<<<64, 256, 0, stream>>>(W_lin, Wlinh, 16384);
  k_f2h<<<384, 256, 0, stream>>>(m1w, m1wh, 2 * 128 * 384);
  k_f2h<<<128, 256, 0, stream>>>(m2w, m2wh, 2 * 128 * 128);
  k_transpose_f2h<<<64, 256, 0, stream>>>(W_gc, WgcTh, 128, 128);

  // ---- feature linear layers ----
  gemm128(src_feat, 128, Wlinh, 128, b_lin, linS, 128, NB, 128, 128, 0);
  gemm128(ngh1_feat, 128, Wlinh, 128, b_lin, lin1, 128, NA, 128, 128, 0);

  // ---- attention calls ----
  auto attn_call = [&](int ci, long rows_total, const float* srcvec,
                       const float* featp, const float* tsrcp, const float* tnghp,
                       const int* idxp, int l, float* outp) {
    for (long r0 = 0; r0 < rows_total; r0 += rows_c) {
      long rem = rows_total - r0;
      int rows = (int)(rem < rows_c ? rem : rows_c);
      gemm128(srcvec + r0 * 128, 128, SWh + (size_t)ci * 520 * 128, 128,
              cbU + ci * 520, (float*)Ubuf, 520, rows, 520, 128, 1);
      k_score<<<rows, 256, 0, stream>>>(Ubuf, featp + r0 * 20 * 128, tsrcp + r0,
                                        tnghp + r0 * 20, idxp + r0 * 20, freq, phase, rows);
      k_pgemm_ln<<<rows / 64, 256, 0, stream>>>(
          Ubuf, Fh + (size_t)ci * 256 * 520, fcb + l * 256, srcvec + r0 * 128,
          te0, lng + l * 256, lnb + l * 256, Pbuf, rows);
      k_merge<<<rows / 64, 256, 0, stream>>>(
          Pbuf, srcvec + r0 * 128, m1wh + (size_t)l * 128 * 384, m1b + l * 128,
          m2wh + (size_t)l * 128 * 128, m2b + l * 128, outp + r0 * 128, rows);
    }
  };
  attn_call(0, NA, lin1, ngh2_feat, ngh1_t, ngh2_t, ngh2_idx, 0, ngh_l1);
  attn_call(1, NB, linS, lin1, src_t, ngh1_t, ngh1_idx, 0, src_l1);
  attn_call(2, NB, src_l1, ngh_l1, src_t, ngh1_t, ngh1_idx, 1, out);

  // ---- autoencoder loss ----
  gemm128(ae_x, 128, WgcTh, 128, nullptr, (float*)xwh, 128, 4096, 128, 128, 1);
  k_transpose_h<<<(4096 * 128 + 255) / 256, 256, 0, stream>>>(xwh, xwTh, 4096, 128);
  {
    dim3 g(4096 / 64, 128 / 64);
    k_mgemm<64, 64><<<g, 256, 0, stream>>>(ae_adj, 4096, xwTh, 4096, b_gc,
                                           (float*)zh, 128, 4096, 128, 4096, 1);
  }
  k_zero<<<1, 1, 0, stream>>>(lacc);
  k_loss_mfma<<<dim3(32, 32), 256, 0, stream>>>(zh, ae_adj, lacc);
  k_final<<<1, 1, 0, stream>>>(lacc, out + (size_t)NB * 128);
}